// Round 8
// baseline (604.027 us; speedup 1.0000x reference)
//
#include <hip/hip_runtime.h>
#include <math.h>

#define NN 50000
#define EE 800000
#define BBG 256
#define HHC 128
#define SEG_CAP 448  // LDS x-cache rows per graph (fp16 packed)
#define ESC 512      // per-graph e-cache entries in LDS
#define NBIN 196     // coarse bins of 256 nodes
#define NBLK 196     // blocks in K1/K3 (4096 edges each)

typedef _Float16 half8 __attribute__((ext_vector_type(8)));
typedef _Float16 half4 __attribute__((ext_vector_type(4)));
typedef _Float16 half2v __attribute__((ext_vector_type(2)));
typedef float f32x4 __attribute__((ext_vector_type(4)));

#if defined(__has_builtin)
#if __has_builtin(__builtin_amdgcn_fdot2)
#define USE_FDOT2 1
#endif
#endif

__device__ __forceinline__ float fdot2f(half2v a, half2v b, float c) {
#ifdef USE_FDOT2
  return __builtin_amdgcn_fdot2(a, b, c, false);
#else
  return fmaf((float)a[0], (float)b[0], fmaf((float)a[1], (float)b[1], c));
#endif
}

__device__ __forceinline__ float fsigm(float x) {
  return __builtin_amdgcn_rcpf(1.f + __expf(-x));
}
__device__ __forceinline__ float ftanh(float x) {
  return 1.f - 2.f * __builtin_amdgcn_rcpf(1.f + __expf(2.f * x));
}

// monotonic float<->uint key for atomicMax-based float max
__device__ __forceinline__ unsigned keyf(float f) {
  unsigned u = __float_as_uint(f);
  return (u & 0x80000000u) ? ~u : (u | 0x80000000u);
}
__device__ __forceinline__ float unkeyf(unsigned k) {
  return (k & 0x80000000u) ? __uint_as_float(k ^ 0x80000000u) : __uint_as_float(~k);
}

__device__ __forceinline__ float4 aff4(float4 v, float4 sc, float4 sh) {
  v.x = fmaxf(fmaf(v.x, sc.x, sh.x), 0.f);
  v.y = fmaxf(fmaf(v.y, sc.y, sh.y), 0.f);
  v.z = fmaxf(fmaf(v.z, sc.z, sh.z), 0.f);
  v.w = fmaxf(fmaf(v.w, sc.w, sh.w), 0.f);
  return v;
}

// ---------------- merged prep: zero | gptr | coarse hist | weight repack | x->fp16 ----
__global__ __launch_bounds__(256) void prep_all_kernel(
    const int* __restrict__ batch,
    const int* __restrict__ ei,
    const float* __restrict__ W0, const float* __restrict__ W1,
    const float* __restrict__ W2, const float* __restrict__ W3,
    const float* __restrict__ Wih0, const float* __restrict__ Whh0,
    const float* __restrict__ WihR, const float* __restrict__ WhhR,
    const float* __restrict__ b0, const float* __restrict__ bR,
    const float* __restrict__ xsrc,
    float* __restrict__ stats, int* __restrict__ gptr, int* __restrict__ partial,
    _Float16* __restrict__ ginWh, _Float16* __restrict__ WT0h,
    _Float16* __restrict__ WTRh, float* __restrict__ bc0, float* __restrict__ bcR,
    _Float16* __restrict__ x16a) {
  __shared__ int hist[NBIN];
  int blk = blockIdx.x, tid = threadIdx.x;
  if (blk == 0) {
    ((float4*)stats)[tid] = make_float4(0.f, 0.f, 0.f, 0.f);  // 1024 floats
    return;
  }
  if (blk <= 196) {  // gptr boundaries
    int i = (blk - 1) * 256 + tid;
    if (i >= NN) return;
    int b = batch[i];
    int prev = (i == 0) ? -1 : batch[i - 1];
    for (int g = prev + 1; g <= b; ++g) gptr[g] = i;
    if (i == NN - 1) {
      for (int g = b + 1; g <= BBG; ++g) gptr[g] = NN;
    }
    return;
  }
  if (blk <= 392) {  // coarse hist
    int b = blk - 197;
    if (tid < NBIN) hist[tid] = 0;
    __syncthreads();
    const int4* dst4 = (const int4*)(ei + EE);
#pragma unroll
    for (int c = 0; c < 4; ++c) {
      int idx = b * 1024 + c * 256 + tid;
      if (idx < EE / 4) {
        int4 d = dst4[idx];
        atomicAdd(&hist[d.x >> 8], 1);
        atomicAdd(&hist[d.y >> 8], 1);
        atomicAdd(&hist[d.z >> 8], 1);
        atomicAdd(&hist[d.w >> 8], 1);
      }
    }
    __syncthreads();
    if (tid < NBIN) partial[tid * NBLK + b] = hist[tid];
    return;
  }
  if (blk >= 2961) {  // x -> fp16 (6250 blocks x 256 = 1,600,000 float4 groups)
    int i = (blk - 2961) * 256 + tid;
    float4 v = ((const float4*)xsrc)[i];
    half4 h;
    h[0] = (_Float16)v.x; h[1] = (_Float16)v.y;
    h[2] = (_Float16)v.z; h[3] = (_Float16)v.w;
    ((half4*)x16a)[i] = h;
    return;
  }
  // weight prep
  int idx = (blk - 393) * 256 + tid;  // [0, 657408)
  if (idx < 65536) {
    int m = idx >> 14;
    int r = idx & 16383;
    const float* W = (m == 0) ? W0 : (m == 1) ? W1 : (m == 2) ? W2 : W3;
    ginWh[idx] = (_Float16)W[r];  // natural [o][k], k contiguous
  } else if (idx < 262144) {
    int t = idx - 65536;
    int k = t >> 9, op = t & 511;
    int j = op >> 2, g = op & 3;
    int row = g * 128 + j;
    float v = (k < 256) ? Wih0[row * 256 + k] : Whh0[row * 128 + (k - 256)];
    WT0h[((k >> 1) << 10) | (op << 1) | (k & 1)] = (_Float16)v;
  } else if (idx < 655360) {
    int t = idx - 262144;
    int l = t >> 17;
    int rem = t & 131071;
    int k = rem >> 9, op = rem & 511;
    int j = op >> 2, g = op & 3;
    int row = g * 128 + j;
    float v = (k < 128) ? WihR[((size_t)l * 512 + row) * 128 + k]
                        : WhhR[((size_t)l * 512 + row) * 128 + (k - 128)];
    WTRh[((size_t)l << 17) | ((k >> 1) << 10) | (op << 1) | (k & 1)] = (_Float16)v;
  } else {
    int t = idx - 655360;
    if (t < 512) {
      bc0[t] = b0[(t & 3) * 128 + (t >> 2)];
    } else {
      int u = t - 512;
      int l = u >> 9, op = u & 511;
      bcR[u] = bR[l * 512 + (op & 3) * 128 + (op >> 2)];
    }
  }
}

// ---- atomic-free CSR build (two-level counting sort) ----

__global__ void scan_partials_kernel(const int* __restrict__ partial,
                                     int* __restrict__ block_base, int* __restrict__ total) {
  __shared__ int buf[256];
  int bin = blockIdx.x, tid = threadIdx.x;
  int v = (tid < NBLK) ? partial[bin * NBLK + tid] : 0;
  buf[tid] = v;
  __syncthreads();
  for (int off = 1; off < 256; off <<= 1) {
    int t = (tid >= off) ? buf[tid - off] : 0;
    __syncthreads();
    buf[tid] += t;
    __syncthreads();
  }
  if (tid < NBLK) block_base[bin * NBLK + tid] = buf[tid] - v;
  if (tid == 255) total[bin] = buf[255];
}

// bucket_scatter with LOCAL scan of total[] (scan_totals kernel removed)
__global__ __launch_bounds__(256) void bucket_scatter_kernel(const int* __restrict__ ei,
                                                             const int* __restrict__ total,
                                                             const int* __restrict__ block_base,
                                                             int* __restrict__ packed) {
  __shared__ int sbuf[256];
  __shared__ int cursor[NBIN];
  int tid = threadIdx.x, b = blockIdx.x;
  int v = (tid < NBIN) ? total[tid] : 0;
  sbuf[tid] = v;
  __syncthreads();
  for (int off = 1; off < 256; off <<= 1) {
    int t = (tid >= off) ? sbuf[tid - off] : 0;
    __syncthreads();
    sbuf[tid] += t;
    __syncthreads();
  }
  if (tid < NBIN) cursor[tid] = (sbuf[tid] - v) + block_base[tid * NBLK + b];
  __syncthreads();
  const int4* src4 = (const int4*)ei;
  const int4* dst4 = (const int4*)(ei + EE);
#pragma unroll
  for (int c = 0; c < 4; ++c) {
    int idx = b * 1024 + c * 256 + tid;
    if (idx < EE / 4) {
      int4 s = src4[idx];
      int4 d = dst4[idx];
      int p;
      p = atomicAdd(&cursor[d.x >> 8], 1); packed[p] = (s.x << 8) | (d.x & 255);
      p = atomicAdd(&cursor[d.y >> 8], 1); packed[p] = (s.y << 8) | (d.y & 255);
      p = atomicAdd(&cursor[d.z >> 8], 1); packed[p] = (s.z << 8) | (d.z & 255);
      p = atomicAdd(&cursor[d.w >> 8], 1); packed[p] = (s.w << 8) | (d.w & 255);
    }
  }
}

// csr_finalize with LOCAL scan of total[] (scan_totals kernel removed)
__global__ __launch_bounds__(256) void csr_finalize_kernel(const int* __restrict__ packed,
                                                           const int* __restrict__ total,
                                                           int* __restrict__ row_start,
                                                           int* __restrict__ csr) {
  __shared__ int fh[256];
  __shared__ int fb[256];
  int bin = blockIdx.x, tid = threadIdx.x;
  // local exclusive scan of total -> e0, e1
  int tv = (tid < NBIN) ? total[tid] : 0;
  fb[tid] = tv;
  __syncthreads();
  for (int off = 1; off < 256; off <<= 1) {
    int t = (tid >= off) ? fb[tid - off] : 0;
    __syncthreads();
    fb[tid] += t;
    __syncthreads();
  }
  int e0 = (bin == 0) ? 0 : fb[bin - 1];
  int e1 = fb[bin];
  __syncthreads();
  fh[tid] = 0;
  __syncthreads();
  for (int e = e0 + tid; e < e1; e += 256) atomicAdd(&fh[packed[e] & 255], 1);
  __syncthreads();
  int v = fh[tid];
  fb[tid] = v;
  __syncthreads();
  for (int off = 1; off < 256; off <<= 1) {
    int t = (tid >= off) ? fb[tid - off] : 0;
    __syncthreads();
    fb[tid] += t;
    __syncthreads();
  }
  int excl = fb[tid] - v;
  int node = bin * 256 + tid;
  if (node < NN) row_start[node] = e0 + excl;
  if (bin == NBIN - 1 && tid == 0) row_start[NN] = EE;
  __syncthreads();
  fb[tid] = excl;  // cursor
  __syncthreads();
  for (int e = e0 + tid; e < e1; e += 256) {
    int p = packed[e];
    int pos = atomicAdd(&fb[p & 255], 1);
    csr[e0 + pos] = p >> 8;
  }
}

// ---------------- fused GIN aggregation + MFMA GEMM ----------------
template <bool AFF>
__global__ __launch_bounds__(256) void agg_gemm_kernel(
    const _Float16* __restrict__ x16, const int* __restrict__ row_start,
    const int* __restrict__ csr,
    const float* __restrict__ stats, const float* __restrict__ gamma,
    const float* __restrict__ beta,
    const _Float16* __restrict__ Wh, const float* __restrict__ bias,
    _Float16* __restrict__ h16out,
    float* __restrict__ ssum, float* __restrict__ ssq) {
  __shared__ _Float16 As[4][16][136];
  __shared__ float sc_s[128], sh_s[128];
  int tid = threadIdx.x;
  if (AFF) {
    if (tid < 128) {
      const float invN = 1.0f / (float)NN;
      float mm = stats[tid] * invN;
      float vv = stats[128 + tid] * invN - mm * mm;
      float rs = rsqrtf(vv + 1e-5f);
      float sc = gamma[tid] * rs;
      sc_s[tid] = sc;
      sh_s[tid] = beta[tid] - mm * sc;
    }
    __syncthreads();
  }
  int tile0 = blockIdx.x * 4;
  // ---- phase A: gather ----
  {
    int nloc = tid >> 4;  // 0..15
    int t = tid & 15;     // channel chunk
    const half8* xh8 = (const half8*)x16;
    float scv[8], shv[8];
    if (AFF) {
#pragma unroll
      for (int f = 0; f < 8; ++f) { scv[f] = sc_s[t * 8 + f]; shv[f] = sh_s[t * 8 + f]; }
    }
    for (int tt = 0; tt < 4; ++tt) {
      int tile = tile0 + tt;
      if (tile >= 3125) break;
      int node = tile * 16 + nloc;
      int s0 = row_start[node], s1 = row_start[node + 1];
      float acc[8] = {0.f, 0.f, 0.f, 0.f, 0.f, 0.f, 0.f, 0.f};
      int j = s0;
      for (; j + 8 <= s1; j += 8) {
        int i0 = csr[j + 0];
        int i1 = csr[j + 1];
        int i2 = csr[j + 2];
        int i3 = csr[j + 3];
        int i4 = csr[j + 4];
        int i5 = csr[j + 5];
        int i6 = csr[j + 6];
        int i7 = csr[j + 7];
        half8 h0 = xh8[(size_t)i0 * 16 + t];
        half8 h1 = xh8[(size_t)i1 * 16 + t];
        half8 h2 = xh8[(size_t)i2 * 16 + t];
        half8 h3 = xh8[(size_t)i3 * 16 + t];
        half8 h4 = xh8[(size_t)i4 * 16 + t];
        half8 h5 = xh8[(size_t)i5 * 16 + t];
        half8 h6 = xh8[(size_t)i6 * 16 + t];
        half8 h7 = xh8[(size_t)i7 * 16 + t];
#pragma unroll
        for (int f = 0; f < 8; ++f) {
          if (AFF) {
            acc[f] += fmaxf(fmaf((float)h0[f], scv[f], shv[f]), 0.f);
            acc[f] += fmaxf(fmaf((float)h1[f], scv[f], shv[f]), 0.f);
            acc[f] += fmaxf(fmaf((float)h2[f], scv[f], shv[f]), 0.f);
            acc[f] += fmaxf(fmaf((float)h3[f], scv[f], shv[f]), 0.f);
            acc[f] += fmaxf(fmaf((float)h4[f], scv[f], shv[f]), 0.f);
            acc[f] += fmaxf(fmaf((float)h5[f], scv[f], shv[f]), 0.f);
            acc[f] += fmaxf(fmaf((float)h6[f], scv[f], shv[f]), 0.f);
            acc[f] += fmaxf(fmaf((float)h7[f], scv[f], shv[f]), 0.f);
          } else {
            acc[f] += (((float)h0[f] + (float)h1[f]) + ((float)h2[f] + (float)h3[f])) +
                      (((float)h4[f] + (float)h5[f]) + ((float)h6[f] + (float)h7[f]));
          }
        }
      }
      if (j + 4 <= s1) {
        int i0 = csr[j + 0];
        int i1 = csr[j + 1];
        int i2 = csr[j + 2];
        int i3 = csr[j + 3];
        half8 h0 = xh8[(size_t)i0 * 16 + t];
        half8 h1 = xh8[(size_t)i1 * 16 + t];
        half8 h2 = xh8[(size_t)i2 * 16 + t];
        half8 h3 = xh8[(size_t)i3 * 16 + t];
#pragma unroll
        for (int f = 0; f < 8; ++f) {
          if (AFF) {
            acc[f] += fmaxf(fmaf((float)h0[f], scv[f], shv[f]), 0.f);
            acc[f] += fmaxf(fmaf((float)h1[f], scv[f], shv[f]), 0.f);
            acc[f] += fmaxf(fmaf((float)h2[f], scv[f], shv[f]), 0.f);
            acc[f] += fmaxf(fmaf((float)h3[f], scv[f], shv[f]), 0.f);
          } else {
            acc[f] += ((float)h0[f] + (float)h1[f]) + ((float)h2[f] + (float)h3[f]);
          }
        }
        j += 4;
      }
      for (; j < s1; ++j) {
        int i = csr[j];
        half8 h = xh8[(size_t)i * 16 + t];
#pragma unroll
        for (int f = 0; f < 8; ++f) {
          float v = (float)h[f];
          if (AFF) v = fmaxf(fmaf(v, scv[f], shv[f]), 0.f);
          acc[f] += v;
        }
      }
      half8 selfh = xh8[(size_t)node * 16 + t];
      half8 hv;
#pragma unroll
      for (int f = 0; f < 8; ++f) {
        float sv = (float)selfh[f];
        if (AFF) sv = fmaxf(fmaf(sv, scv[f], shv[f]), 0.f);
        hv[f] = (_Float16)(acc[f] + sv);
      }
      *(half8*)&As[tt][nloc][t * 8] = hv;
    }
  }
  __syncthreads();
  // ---- phase B: MFMA ----
  int w = tid >> 6, l = tid & 63;
  int lr = l & 15, lg = l >> 4;
  int cb = w * 32;
  half8 bf0[4], bf1[4];
#pragma unroll
  for (int ks = 0; ks < 4; ++ks) {
    int k = ks * 32 + lg * 8;
    bf0[ks] = *(const half8*)(Wh + (size_t)(cb + lr) * 128 + k);
    bf1[ks] = *(const half8*)(Wh + (size_t)(cb + 16 + lr) * 128 + k);
  }
  float bv0 = bias[cb + lr], bv1 = bias[cb + 16 + lr];
  float ps0 = 0.f, pq0 = 0.f, ps1 = 0.f, pq1 = 0.f;
  for (int tt = 0; tt < 4; ++tt) {
    int tile = tile0 + tt;
    if (tile >= 3125) break;
    half8 af[4];
#pragma unroll
    for (int ks = 0; ks < 4; ++ks) {
      af[ks] = *(const half8*)&As[tt][lr][ks * 32 + lg * 8];
    }
    f32x4 acc0 = {0.f, 0.f, 0.f, 0.f};
    f32x4 acc1 = {0.f, 0.f, 0.f, 0.f};
#pragma unroll
    for (int ks = 0; ks < 4; ++ks) {
      acc0 = __builtin_amdgcn_mfma_f32_16x16x32_f16(af[ks], bf0[ks], acc0, 0, 0, 0);
      acc1 = __builtin_amdgcn_mfma_f32_16x16x32_f16(af[ks], bf1[ks], acc1, 0, 0, 0);
    }
#pragma unroll
    for (int i = 0; i < 4; ++i) {
      int rr = tile * 16 + lg * 4 + i;
      float v0 = acc0[i] + bv0;
      float v1 = acc1[i] + bv1;
      h16out[(size_t)rr * 128 + cb + lr] = (_Float16)v0;
      h16out[(size_t)rr * 128 + cb + 16 + lr] = (_Float16)v1;
      ps0 += v0; pq0 += v0 * v0;
      ps1 += v1; pq1 += v1 * v1;
    }
  }
  ps0 += __shfl_xor(ps0, 16); ps0 += __shfl_xor(ps0, 32);
  pq0 += __shfl_xor(pq0, 16); pq0 += __shfl_xor(pq0, 32);
  ps1 += __shfl_xor(ps1, 16); ps1 += __shfl_xor(ps1, 32);
  pq1 += __shfl_xor(pq1, 16); pq1 += __shfl_xor(pq1, 32);
  if (lg == 0) {
    atomicAdd(&ssum[cb + lr], ps0);
    atomicAdd(&ssq[cb + lr], pq0);
    atomicAdd(&ssum[cb + 16 + lr], ps1);
    atomicAdd(&ssq[cb + 16 + lr], pq1);
  }
}

// ---------------- MFMA GIN GEMM (BN+relu on fp16 A) ----------------
template <bool BN>
__global__ __launch_bounds__(256) void gemm_gin_mfma_kernel(
    const _Float16* __restrict__ A16,
    const _Float16* __restrict__ Wh,
    const float* __restrict__ bias,
    const float* __restrict__ stats, const float* __restrict__ gamma,
    const float* __restrict__ beta,
    _Float16* __restrict__ h16out,
    float* __restrict__ ssum, float* __restrict__ ssq) {
  __shared__ float bsc_s[128], bsh_s[128];
  int tid = threadIdx.x;
  if (BN) {
    if (tid < 128) {
      const float invN = 1.0f / (float)NN;
      float mm = stats[tid] * invN;
      float vv = stats[128 + tid] * invN - mm * mm;
      float rs = rsqrtf(vv + 1e-5f);
      float sc = gamma[tid] * rs;
      bsc_s[tid] = sc;
      bsh_s[tid] = beta[tid] - mm * sc;
    }
    __syncthreads();
  }
  int w = tid >> 6, l = tid & 63;
  int lr = l & 15, lg = l >> 4;
  int cb = w * 32;
  half8 bf0[4], bf1[4];
#pragma unroll
  for (int ks = 0; ks < 4; ++ks) {
    int k = ks * 32 + lg * 8;
    bf0[ks] = *(const half8*)(Wh + (size_t)(cb + lr) * 128 + k);
    bf1[ks] = *(const half8*)(Wh + (size_t)(cb + 16 + lr) * 128 + k);
  }
  float bv0 = bias[cb + lr], bv1 = bias[cb + 16 + lr];
  float ps0 = 0.f, pq0 = 0.f, ps1 = 0.f, pq1 = 0.f;
  int t0 = blockIdx.x * 4;
  for (int t = 0; t < 4; ++t) {
    int tile = t0 + t;
    if (tile >= 3125) break;
    int r = tile * 16 + lr;
    half8 af[4];
#pragma unroll
    for (int ks = 0; ks < 4; ++ks) {
      int k0 = ks * 32 + lg * 8;
      half8 ah = *(const half8*)(A16 + (size_t)r * 128 + k0);
      if constexpr (BN) {
        float4 s0 = *(const float4*)&bsc_s[k0];
        float4 s1 = *(const float4*)&bsc_s[k0 + 4];
        float4 h0 = *(const float4*)&bsh_s[k0];
        float4 h1 = *(const float4*)&bsh_s[k0 + 4];
        half8 o;
        o[0] = (_Float16)fmaxf(fmaf((float)ah[0], s0.x, h0.x), 0.f);
        o[1] = (_Float16)fmaxf(fmaf((float)ah[1], s0.y, h0.y), 0.f);
        o[2] = (_Float16)fmaxf(fmaf((float)ah[2], s0.z, h0.z), 0.f);
        o[3] = (_Float16)fmaxf(fmaf((float)ah[3], s0.w, h0.w), 0.f);
        o[4] = (_Float16)fmaxf(fmaf((float)ah[4], s1.x, h1.x), 0.f);
        o[5] = (_Float16)fmaxf(fmaf((float)ah[5], s1.y, h1.y), 0.f);
        o[6] = (_Float16)fmaxf(fmaf((float)ah[6], s1.z, h1.z), 0.f);
        o[7] = (_Float16)fmaxf(fmaf((float)ah[7], s1.w, h1.w), 0.f);
        af[ks] = o;
      } else {
        af[ks] = ah;
      }
    }
    f32x4 acc0 = {0.f, 0.f, 0.f, 0.f};
    f32x4 acc1 = {0.f, 0.f, 0.f, 0.f};
#pragma unroll
    for (int ks = 0; ks < 4; ++ks) {
      acc0 = __builtin_amdgcn_mfma_f32_16x16x32_f16(af[ks], bf0[ks], acc0, 0, 0, 0);
      acc1 = __builtin_amdgcn_mfma_f32_16x16x32_f16(af[ks], bf1[ks], acc1, 0, 0, 0);
    }
#pragma unroll
    for (int i = 0; i < 4; ++i) {
      int rr = tile * 16 + lg * 4 + i;
      float v0 = acc0[i] + bv0;
      float v1 = acc1[i] + bv1;
      h16out[(size_t)rr * 128 + cb + lr] = (_Float16)v0;
      h16out[(size_t)rr * 128 + cb + 16 + lr] = (_Float16)v1;
      ps0 += v0; pq0 += v0 * v0;
      ps1 += v1; pq1 += v1 * v1;
    }
  }
  ps0 += __shfl_xor(ps0, 16); ps0 += __shfl_xor(ps0, 32);
  pq0 += __shfl_xor(pq0, 16); pq0 += __shfl_xor(pq0, 32);
  ps1 += __shfl_xor(ps1, 16); ps1 += __shfl_xor(ps1, 32);
  pq1 += __shfl_xor(pq1, 16); pq1 += __shfl_xor(pq1, 32);
  if (lg == 0) {
    atomicAdd(&ssum[cb + lr], ps0);
    atomicAdd(&ssq[cb + lr], pq0);
    atomicAdd(&ssum[cb + 16 + lr], ps1);
    atomicAdd(&ssq[cb + 16 + lr], pq1);
  }
}

// ---------------- fused Set2Set v9: LSTM weights held in REGISTERS across all
// 4 steps (one coalesced load at kernel start; zero weight traffic afterwards).
// fp16 shadow state, atomic max/sum, fp16 LDS x-cache, step-0 skip. ----------

// activation (+ fp16 shadow update); SKIPV = gates are just the bias
#define S2S_ACT(CELLV, BIASP, SKIPV)                                           \
  if (tid < 128) {                                                             \
    int j = tid;                                                               \
    float4 ga = *(const float4*)&(BIASP)[4 * j];                               \
    if (!(SKIPV)) {                                                            \
      _Pragma("unroll")                                                        \
      for (int s = 0; s < 16; ++s) {                                           \
        float4 wv = *(const float4*)&wpart[s][4 * j];                          \
        ga.x += wv.x; ga.y += wv.y; ga.z += wv.z; ga.w += wv.w;                \
      }                                                                        \
    }                                                                          \
    float cp = ccs[CELLV][j];                                                  \
    float si = fsigm(ga.x), sf = fsigm(ga.y), so = fsigm(ga.w);                \
    float cn = sf * cp + si * ftanh(ga.z);                                     \
    ccs[CELLV][j] = cn;                                                        \
    float hn = so * ftanh(cn);                                                 \
    hcs[CELLV][j] = hn;                                                        \
    h16s[CELLV][j] = (_Float16)hn;                                             \
    if ((CELLV) == 3 && j == 0) { smax_u = 0u; ssum_s = 0.f; }                 \
  }                                                                            \
  __syncthreads();

// recurrent cell (1..3): matvec from register weights + activation
#define S2S_CELL_R(CIDX, WARR)                                                 \
  {                                                                            \
    float a0 = 0.f, a1 = 0.f, a2 = 0.f, a3 = 0.f;                              \
    float a4 = 0.f, a5 = 0.f, a6 = 0.f, a7 = 0.f;                              \
    if (step != 0 || s_ < 8) {                                                 \
      _Pragma("unroll")                                                        \
      for (int k2 = 0; k2 < 8; ++k2) {                                         \
        int kk = (s_ * 8 + k2) << 1;                                           \
        half2v i2 = (kk < 128) ? *(const half2v*)&h16s[(CIDX) - 1][kk]         \
                               : *(const half2v*)&h16s[CIDX][kk - 128];        \
        uint4 wa = WARR[2 * k2], wc = WARR[2 * k2 + 1];                        \
        a0 = fdot2f(i2, __builtin_bit_cast(half2v, wa.x), a0);                 \
        a1 = fdot2f(i2, __builtin_bit_cast(half2v, wa.y), a1);                 \
        a2 = fdot2f(i2, __builtin_bit_cast(half2v, wa.z), a2);                 \
        a3 = fdot2f(i2, __builtin_bit_cast(half2v, wa.w), a3);                 \
        a4 = fdot2f(i2, __builtin_bit_cast(half2v, wc.x), a4);                 \
        a5 = fdot2f(i2, __builtin_bit_cast(half2v, wc.y), a5);                 \
        a6 = fdot2f(i2, __builtin_bit_cast(half2v, wc.z), a6);                 \
        a7 = fdot2f(i2, __builtin_bit_cast(half2v, wc.w), a7);                 \
      }                                                                        \
    }                                                                          \
    *(float4*)&wpart[s_][cg << 3] = make_float4(a0, a1, a2, a3);               \
    *(float4*)(&wpart[s_][cg << 3] + 4) = make_float4(a4, a5, a6, a7);         \
    __syncthreads();                                                           \
    S2S_ACT(CIDX, bcR + ((CIDX) - 1) * 512, false)                             \
  }

__global__ void __launch_bounds__(1024) set2set_kernel(
    const _Float16* __restrict__ x, const int* __restrict__ gptr,
    const float* __restrict__ stats, const float* __restrict__ gamma,
    const float* __restrict__ beta,
    const _Float16* __restrict__ WT0h, const _Float16* __restrict__ WTRh,
    const float* __restrict__ bc0, const float* __restrict__ bcR,
    float* __restrict__ ebuf,
    const float* __restrict__ linW, const float* __restrict__ linb,
    float* __restrict__ out) {
  __shared__ half2v xs[SEG_CAP * 64];   // 114688 B (448 rows, fp16-packed)
  __shared__ float wpart[16][512];      // 32 KB (aliased as rpart in attention)
  __shared__ float hcs[4][128];
  __shared__ float ccs[4][128];
  __shared__ _Float16 h16s[4][128];     // fp16 shadow of hcs (matvec operand)
  __shared__ _Float16 q16s[256];        // fp16 shadow of qst
  __shared__ float qst[256];
  __shared__ float es[ESC];             // 2 KB
  __shared__ float bsc[128], bsh[128];
  __shared__ unsigned smax_u;
  __shared__ float ssum_s;
  __shared__ float fred[2][4];

  int g = blockIdx.x, tid = threadIdx.x;
  int w16 = tid >> 6, lane = tid & 63;
  int s_ = w16, cg = lane;  // fixed K-slice per wave (rotation dropped: weights now load once)

  // ---- load this wave's LSTM weight slice into registers (held all 4 steps) ----
  // cell0: 12 k2-pairs x {wa,wc} = 24 uint4 (96 VGPR); cells1-3: 16 uint4 each.
  uint4 w0r[24], w1r[16], w2r[16], w3r[16];
  {
    const char* b0p = (const char*)WT0h + (size_t)(s_ * 12) * 2048 + (cg << 5);
#pragma unroll
    for (int k2 = 0; k2 < 12; ++k2) {
      w0r[2 * k2]     = *(const uint4*)(b0p + (size_t)k2 * 2048);
      w0r[2 * k2 + 1] = *(const uint4*)(b0p + (size_t)k2 * 2048 + 16);
    }
    const char* bRp = (const char*)WTRh + (size_t)(s_ * 8) * 2048 + (cg << 5);
#pragma unroll
    for (int k2 = 0; k2 < 8; ++k2) {
      w1r[2 * k2]     = *(const uint4*)(bRp + (size_t)k2 * 2048);
      w1r[2 * k2 + 1] = *(const uint4*)(bRp + (size_t)k2 * 2048 + 16);
    }
    bRp += 262144;
#pragma unroll
    for (int k2 = 0; k2 < 8; ++k2) {
      w2r[2 * k2]     = *(const uint4*)(bRp + (size_t)k2 * 2048);
      w2r[2 * k2 + 1] = *(const uint4*)(bRp + (size_t)k2 * 2048 + 16);
    }
    bRp += 262144;
#pragma unroll
    for (int k2 = 0; k2 < 8; ++k2) {
      w3r[2 * k2]     = *(const uint4*)(bRp + (size_t)k2 * 2048);
      w3r[2 * k2 + 1] = *(const uint4*)(bRp + (size_t)k2 * 2048 + 16);
    }
  }

  // init
  if (tid < 128) {
    const float invN = 1.0f / (float)NN;
    float mm = stats[tid] * invN;
    float vv = stats[128 + tid] * invN - mm * mm;
    float rs = rsqrtf(vv + 1e-5f);
    float sc = gamma[tid] * rs;
    bsc[tid] = sc;
    bsh[tid] = beta[tid] - mm * sc;
#pragma unroll
    for (int l = 0; l < 4; ++l) {
      hcs[l][tid] = 0.f; ccs[l][tid] = 0.f; h16s[l][tid] = (_Float16)0.f;
    }
  }
  if (tid < 256) { qst[tid] = 0.f; q16s[tid] = (_Float16)0.f; }
  __syncthreads();

  int s0 = gptr[g], s1 = gptr[g + 1];
  int seg = s1 - s0;
  int ncache = seg < SEG_CAP ? seg : SEG_CAP;
  const half2v* xh = (const half2v*)x;
  float sc0 = bsc[2 * lane], sc1 = bsc[2 * lane + 1];
  float sh0 = bsh[2 * lane], sh1 = bsh[2 * lane + 1];
  // stage segment into LDS once (BN4-transformed, fp16-packed); one row per wave
  for (int n = w16; n < ncache; n += 16) {
    half2v v = xh[(size_t)(s0 + n) * 64 + lane];
    half2v h;
    h[0] = (_Float16)fmaxf(fmaf((float)v[0], sc0, sh0), 0.f);
    h[1] = (_Float16)fmaxf(fmaf((float)v[1], sc1, sh1), 0.f);
    xs[n * 64 + lane] = h;
  }
  __syncthreads();

  for (int step = 0; step < 4; ++step) {
    // ---- cell 0 ----
    {
      bool skipmv = (step == 0);  // all inputs exactly zero at step 0
      if (!skipmv) {
        float a0 = 0.f, a1 = 0.f, a2 = 0.f, a3 = 0.f;
        float a4 = 0.f, a5 = 0.f, a6 = 0.f, a7 = 0.f;
#pragma unroll
        for (int k2 = 0; k2 < 12; ++k2) {
          int kk = (s_ * 12 + k2) << 1;
          half2v i2 = (kk < 256) ? *(const half2v*)&q16s[kk]
                                 : *(const half2v*)&h16s[0][kk - 256];
          uint4 wa = w0r[2 * k2], wc = w0r[2 * k2 + 1];
          a0 = fdot2f(i2, __builtin_bit_cast(half2v, wa.x), a0);
          a1 = fdot2f(i2, __builtin_bit_cast(half2v, wa.y), a1);
          a2 = fdot2f(i2, __builtin_bit_cast(half2v, wa.z), a2);
          a3 = fdot2f(i2, __builtin_bit_cast(half2v, wa.w), a3);
          a4 = fdot2f(i2, __builtin_bit_cast(half2v, wc.x), a4);
          a5 = fdot2f(i2, __builtin_bit_cast(half2v, wc.y), a5);
          a6 = fdot2f(i2, __builtin_bit_cast(half2v, wc.z), a6);
          a7 = fdot2f(i2, __builtin_bit_cast(half2v, wc.w), a7);
        }
        *(float4*)&wpart[s_][cg << 3] = make_float4(a0, a1, a2, a3);
        *(float4*)(&wpart[s_][cg << 3] + 4) = make_float4(a4, a5, a6, a7);
        __syncthreads();
      }
      S2S_ACT(0, bc0, skipmv)
    }
    // ---- cells 1..3 ----
    S2S_CELL_R(1, w1r)
    S2S_CELL_R(2, w2r)
    S2S_CELL_R(3, w3r)

    // ---- attention, q = new h[3]; x from fp16 LDS cache ----
    float* rpart = &wpart[0][0];  // alias: time-disjoint with matvec
    float qx = hcs[3][2 * lane], qy = hcs[3][2 * lane + 1];
    half2v q2; q2[0] = (_Float16)qx; q2[1] = (_Float16)qy;
    // pass 1: e + max (block max via monotonic-key atomicMax, 1 barrier)
    float wmax = -3.0e38f;
    for (int n = w16; n < seg; n += 16) {
      float e;
      if (n < ncache) {
        e = fdot2f(xs[n * 64 + lane], q2, 0.f);
      } else {
        half2v v = xh[(size_t)(s0 + n) * 64 + lane];
        float vx = fmaxf(fmaf((float)v[0], sc0, sh0), 0.f);
        float vy = fmaxf(fmaf((float)v[1], sc1, sh1), 0.f);
        e = vx * qx + vy * qy;
      }
#pragma unroll
      for (int sh = 32; sh; sh >>= 1) e += __shfl_xor(e, sh);
      if (lane == 0) { if (n < ESC) es[n] = e; else ebuf[s0 + n] = e; }
      wmax = fmaxf(wmax, e);
    }
    if (lane == 0) atomicMax(&smax_u, keyf(wmax));
    __syncthreads();
    float m = unkeyf(smax_u);
    // pass 2: sum exp (atomicAdd, 1 barrier); cache exp for pass 3
    float loc = 0.f;
    for (int n = tid; n < seg; n += 1024) {
      float e = (n < ESC) ? es[n] : ebuf[s0 + n];
      float ex = __expf(e - m);
      if (n < ESC) es[n] = ex; else ebuf[s0 + n] = ex;
      loc += ex;
    }
#pragma unroll
    for (int sh = 32; sh; sh >>= 1) loc += __shfl_xor(loc, sh);
    if (lane == 0) atomicAdd(&ssum_s, loc);
    __syncthreads();
    float inv = 1.0f / ssum_s;
    // pass 3: r = sum a*x
    float rx = 0.f, ry = 0.f;
    for (int n = w16; n < seg; n += 16) {
      float ex = (n < ESC) ? es[n] : ebuf[s0 + n];
      float coef = ex * inv;
      float vx, vy;
      if (n < ncache) {
        half2v v2 = xs[n * 64 + lane];
        vx = (float)v2[0]; vy = (float)v2[1];
      } else {
        half2v v = xh[(size_t)(s0 + n) * 64 + lane];
        vx = fmaxf(fmaf((float)v[0], sc0, sh0), 0.f);
        vy = fmaxf(fmaf((float)v[1], sc1, sh1), 0.f);
      }
      rx += coef * vx; ry += coef * vy;
    }
    rpart[w16 * 128 + 2 * lane] = rx;
    rpart[w16 * 128 + 2 * lane + 1] = ry;
    __syncthreads();
    if (tid < 128) {
      float r = 0.f;
#pragma unroll
      for (int t = 0; t < 16; ++t) r += rpart[t * 128 + tid];
      float h3 = hcs[3][tid];
      qst[tid] = h3;
      qst[128 + tid] = r;
      q16s[tid] = (_Float16)h3;
      q16s[128 + tid] = (_Float16)r;
    }
    __syncthreads();
  }
  // ---- final linear ----
  if (tid < 256) {
    float val = qst[tid];
    float p0 = val * linW[tid];
    float p1 = val * linW[256 + tid];
#pragma unroll
    for (int sh = 32; sh; sh >>= 1) { p0 += __shfl_xor(p0, sh); p1 += __shfl_xor(p1, sh); }
    if (lane == 0) { fred[0][w16] = p0; fred[1][w16] = p1; }
  }
  __syncthreads();
  if (tid == 0) {
    out[2 * g + 0] = fred[0][0] + fred[0][1] + fred[0][2] + fred[0][3] + linb[0];
    out[2 * g + 1] = fred[1][0] + fred[1][1] + fred[1][2] + fred[1][3] + linb[1];
  }
}

// ---------------- launch ----------------

extern "C" void kernel_launch(void* const* d_in, const int* in_sizes, int n_in,
                              void* d_out, int out_size, void* d_ws, size_t ws_size,
                              hipStream_t stream) {
  const float* x = (const float*)d_in[0];
  const int* ei = (const int*)d_in[1];
  const int* batch = (const int*)d_in[2];
  const float* gW[4]  = {(const float*)d_in[3],  (const float*)d_in[7],
                         (const float*)d_in[11], (const float*)d_in[15]};
  const float* gb[4]  = {(const float*)d_in[4],  (const float*)d_in[8],
                         (const float*)d_in[12], (const float*)d_in[16]};
  const float* gga[4] = {(const float*)d_in[5],  (const float*)d_in[9],
                         (const float*)d_in[13], (const float*)d_in[17]};
  const float* gbe[4] = {(const float*)d_in[6],  (const float*)d_in[10],
                         (const float*)d_in[14], (const float*)d_in[18]};
  const float* Wih0 = (const float*)d_in[19];
  const float* Whh0 = (const float*)d_in[20];
  const float* b0   = (const float*)d_in[21];
  const float* WihR = (const float*)d_in[22];
  const float* WhhR = (const float*)d_in[23];
  const float* bR   = (const float*)d_in[24];
  const float* linW = (const float*)d_in[25];
  const float* linb = (const float*)d_in[26];
  float* out = (float*)d_out;

  char* base = (char*)d_ws;
  size_t off = 0;
  auto allocf = [&](size_t n) { float* p = (float*)(base + off); off += n * sizeof(float); return p; };
  _Float16* bufA = (_Float16*)(base + off); off += 6400000 * 2;  // prep x16 / gemm4 out
  _Float16* bufB = (_Float16*)(base + off); off += 6400000 * 2;  // aggemm1 out / aggemm2 out
  _Float16* bufC = (_Float16*)(base + off); off += 6400000 * 2;  // gemm2 out
  _Float16* ginWh = (_Float16*)(base + off); off += 65536 * 2;
  _Float16* WT0h = (_Float16*)(base + off); off += 196608 * 2;
  _Float16* WTRh = (_Float16*)(base + off); off += 393216 * 2;
  float* bc0   = allocf(512);
  float* bcR   = allocf(1536);
  float* ebuf  = allocf(50000);
  // ---- zero region: stats only (1024 floats = 256 float4) ----
  float* stats = allocf(1024);     // 4 x (sum128|sq128)
  // ---- ints (all fully written before read; no zeroing needed) ----
  int* row_start = (int*)(base + off); off += 50004 * 4;
  int* gptr = (int*)(base + off); off += 260 * 4;
  int* csr = (int*)(base + off); off += 800000 * 4;
  int* packed = (int*)(base + off); off += 800000 * 4;
  int* partial = (int*)(base + off); off += NBIN * NBLK * 4;
  int* block_base = (int*)(base + off); off += NBIN * NBLK * 4;
  int* total = (int*)(base + off); off += 256 * 4;
  (void)ws_size; (void)in_sizes; (void)n_in; (void)out_size;

  // merged prep: zero | gptr | hist | weight repack | x->fp16
  prep_all_kernel<<<9211, 256, 0, stream>>>(batch, ei, gW[0], gW[1], gW[2], gW[3],
                                            Wih0, Whh0, WihR, WhhR, b0, bR, x,
                                            stats, gptr, partial, ginWh, WT0h, WTRh,
                                            bc0, bcR, bufA);
  scan_partials_kernel<<<NBIN, 256, 0, stream>>>(partial, block_base, total);
  bucket_scatter_kernel<<<NBLK, 256, 0, stream>>>(ei, total, block_base, packed);
  csr_finalize_kernel<<<NBIN, 256, 0, stream>>>(packed, total, row_start, csr);

  // GIN layer 1: fused gather+gemm1 (reads bufA, writes bufB), stats0
  agg_gemm_kernel<false><<<782, 256, 0, stream>>>(
      bufA, row_start, csr,
      nullptr, nullptr, nullptr,
      ginWh + 0 * 16384, gb[0],
      bufB, stats + 0, stats + 128);
  // gemm2: BN1+relu on bufB, writes bufC, stats1
  gemm_gin_mfma_kernel<true><<<782, 256, 0, stream>>>(
      bufB, ginWh + 1 * 16384, gb[1],
      stats + 0, gga[0], gbe[0],
      bufC, stats + 256, stats + 384);
  // GIN layer 2: fused gather(BN2+relu on bufC)+gemm3 (writes bufB), stats2
  agg_gemm_kernel<true><<<782, 256, 0, stream>>>(
      bufC, row_start, csr,
      stats + 256, gga[1], gbe[1],
      ginWh + 2 * 16384, gb[2],
      bufB, stats + 512, stats + 640);
  // gemm4: BN3+relu on bufB, writes bufA (set2set input), stats3
  gemm_gin_mfma_kernel<true><<<782, 256, 0, stream>>>(
      bufB, ginWh + 3 * 16384, gb[3],
      stats + 512, gga[2], gbe[2],
      bufA, stats + 768, stats + 896);
  // bufA holds pre-BN4 features (fp16); BN4 fused into set2set x staging

  // fused Set2Set v9 (weights-in-registers)
  set2set_kernel<<<256, 1024, 0, stream>>>(bufA, gptr, stats + 768, gga[3], gbe[3],
                                           WT0h, WTRh, bc0, bcR, ebuf, linW, linb, out);
}

// Round 10
// 440.792 us; speedup vs baseline: 1.3703x; 1.3703x over previous
//
#include <hip/hip_runtime.h>
#include <math.h>

#define NN 50000
#define EE 800000
#define BBG 256
#define HHC 128
#define SEG2 144   // LDS x-cache rows per graph (2 graphs/block, fp16 packed)
#define ESC2 256   // per-graph e-cache entries in LDS
#define NBIN 196   // coarse bins of 256 nodes
#define NBLK 196   // blocks in K1/K3 (4096 edges each)

typedef _Float16 half8 __attribute__((ext_vector_type(8)));
typedef _Float16 half4 __attribute__((ext_vector_type(4)));
typedef _Float16 half2v __attribute__((ext_vector_type(2)));
typedef float f32x4 __attribute__((ext_vector_type(4)));

#if defined(__has_builtin)
#if __has_builtin(__builtin_amdgcn_fdot2)
#define USE_FDOT2 1
#endif
#endif

__device__ __forceinline__ float fdot2f(half2v a, half2v b, float c) {
#ifdef USE_FDOT2
  return __builtin_amdgcn_fdot2(a, b, c, false);
#else
  return fmaf((float)a[0], (float)b[0], fmaf((float)a[1], (float)b[1], c));
#endif
}

__device__ __forceinline__ float fsigm(float x) {
  return __builtin_amdgcn_rcpf(1.f + __expf(-x));
}
__device__ __forceinline__ float ftanh(float x) {
  return 1.f - 2.f * __builtin_amdgcn_rcpf(1.f + __expf(2.f * x));
}

// monotonic float<->uint key for atomicMax-based float max
__device__ __forceinline__ unsigned keyf(float f) {
  unsigned u = __float_as_uint(f);
  return (u & 0x80000000u) ? ~u : (u | 0x80000000u);
}
__device__ __forceinline__ float unkeyf(unsigned k) {
  return (k & 0x80000000u) ? __uint_as_float(k ^ 0x80000000u) : __uint_as_float(~k);
}

__device__ __forceinline__ float4 aff4(float4 v, float4 sc, float4 sh) {
  v.x = fmaxf(fmaf(v.x, sc.x, sh.x), 0.f);
  v.y = fmaxf(fmaf(v.y, sc.y, sh.y), 0.f);
  v.z = fmaxf(fmaf(v.z, sc.z, sh.z), 0.f);
  v.w = fmaxf(fmaf(v.w, sc.w, sh.w), 0.f);
  return v;
}

// ---------------- merged prep: zero | gptr | coarse hist | weight repack | x->fp16 ----
__global__ __launch_bounds__(256) void prep_all_kernel(
    const int* __restrict__ batch,
    const int* __restrict__ ei,
    const float* __restrict__ W0, const float* __restrict__ W1,
    const float* __restrict__ W2, const float* __restrict__ W3,
    const float* __restrict__ Wih0, const float* __restrict__ Whh0,
    const float* __restrict__ WihR, const float* __restrict__ WhhR,
    const float* __restrict__ b0, const float* __restrict__ bR,
    const float* __restrict__ xsrc,
    float* __restrict__ stats, int* __restrict__ gptr, int* __restrict__ partial,
    _Float16* __restrict__ ginWh, _Float16* __restrict__ WT0h,
    _Float16* __restrict__ WTRh, float* __restrict__ bc0, float* __restrict__ bcR,
    _Float16* __restrict__ x16a) {
  __shared__ int hist[NBIN];
  int blk = blockIdx.x, tid = threadIdx.x;
  if (blk == 0) {
    ((float4*)stats)[tid] = make_float4(0.f, 0.f, 0.f, 0.f);  // 1024 floats
    return;
  }
  if (blk <= 196) {  // gptr boundaries
    int i = (blk - 1) * 256 + tid;
    if (i >= NN) return;
    int b = batch[i];
    int prev = (i == 0) ? -1 : batch[i - 1];
    for (int g = prev + 1; g <= b; ++g) gptr[g] = i;
    if (i == NN - 1) {
      for (int g = b + 1; g <= BBG; ++g) gptr[g] = NN;
    }
    return;
  }
  if (blk <= 392) {  // coarse hist
    int b = blk - 197;
    if (tid < NBIN) hist[tid] = 0;
    __syncthreads();
    const int4* dst4 = (const int4*)(ei + EE);
#pragma unroll
    for (int c = 0; c < 4; ++c) {
      int idx = b * 1024 + c * 256 + tid;
      if (idx < EE / 4) {
        int4 d = dst4[idx];
        atomicAdd(&hist[d.x >> 8], 1);
        atomicAdd(&hist[d.y >> 8], 1);
        atomicAdd(&hist[d.z >> 8], 1);
        atomicAdd(&hist[d.w >> 8], 1);
      }
    }
    __syncthreads();
    if (tid < NBIN) partial[tid * NBLK + b] = hist[tid];
    return;
  }
  if (blk >= 2961) {  // x -> fp16 (6250 blocks x 256 = 1,600,000 float4 groups)
    int i = (blk - 2961) * 256 + tid;
    float4 v = ((const float4*)xsrc)[i];
    half4 h;
    h[0] = (_Float16)v.x; h[1] = (_Float16)v.y;
    h[2] = (_Float16)v.z; h[3] = (_Float16)v.w;
    ((half4*)x16a)[i] = h;
    return;
  }
  // weight prep
  int idx = (blk - 393) * 256 + tid;  // [0, 657408)
  if (idx < 65536) {
    int m = idx >> 14;
    int r = idx & 16383;
    const float* W = (m == 0) ? W0 : (m == 1) ? W1 : (m == 2) ? W2 : W3;
    ginWh[idx] = (_Float16)W[r];  // natural [o][k], k contiguous
  } else if (idx < 262144) {
    int t = idx - 65536;
    int k = t >> 9, op = t & 511;
    int j = op >> 2, g = op & 3;
    int row = g * 128 + j;
    float v = (k < 256) ? Wih0[row * 256 + k] : Whh0[row * 128 + (k - 256)];
    WT0h[((k >> 1) << 10) | (op << 1) | (k & 1)] = (_Float16)v;
  } else if (idx < 655360) {
    int t = idx - 262144;
    int l = t >> 17;
    int rem = t & 131071;
    int k = rem >> 9, op = rem & 511;
    int j = op >> 2, g = op & 3;
    int row = g * 128 + j;
    float v = (k < 128) ? WihR[((size_t)l * 512 + row) * 128 + k]
                        : WhhR[((size_t)l * 512 + row) * 128 + (k - 128)];
    WTRh[((size_t)l << 17) | ((k >> 1) << 10) | (op << 1) | (k & 1)] = (_Float16)v;
  } else {
    int t = idx - 655360;
    if (t < 512) {
      bc0[t] = b0[(t & 3) * 128 + (t >> 2)];
    } else {
      int u = t - 512;
      int l = u >> 9, op = u & 511;
      bcR[u] = bR[l * 512 + (op & 3) * 128 + (op >> 2)];
    }
  }
}

// ---- atomic-free CSR build (two-level counting sort) ----

__global__ void scan_partials_kernel(const int* __restrict__ partial,
                                     int* __restrict__ block_base, int* __restrict__ total) {
  __shared__ int buf[256];
  int bin = blockIdx.x, tid = threadIdx.x;
  int v = (tid < NBLK) ? partial[bin * NBLK + tid] : 0;
  buf[tid] = v;
  __syncthreads();
  for (int off = 1; off < 256; off <<= 1) {
    int t = (tid >= off) ? buf[tid - off] : 0;
    __syncthreads();
    buf[tid] += t;
    __syncthreads();
  }
  if (tid < NBLK) block_base[bin * NBLK + tid] = buf[tid] - v;
  if (tid == 255) total[bin] = buf[255];
}

// bucket_scatter with LOCAL scan of total[]
__global__ __launch_bounds__(256) void bucket_scatter_kernel(const int* __restrict__ ei,
                                                             const int* __restrict__ total,
                                                             const int* __restrict__ block_base,
                                                             int* __restrict__ packed) {
  __shared__ int sbuf[256];
  __shared__ int cursor[NBIN];
  int tid = threadIdx.x, b = blockIdx.x;
  int v = (tid < NBIN) ? total[tid] : 0;
  sbuf[tid] = v;
  __syncthreads();
  for (int off = 1; off < 256; off <<= 1) {
    int t = (tid >= off) ? sbuf[tid - off] : 0;
    __syncthreads();
    sbuf[tid] += t;
    __syncthreads();
  }
  if (tid < NBIN) cursor[tid] = (sbuf[tid] - v) + block_base[tid * NBLK + b];
  __syncthreads();
  const int4* src4 = (const int4*)ei;
  const int4* dst4 = (const int4*)(ei + EE);
#pragma unroll
  for (int c = 0; c < 4; ++c) {
    int idx = b * 1024 + c * 256 + tid;
    if (idx < EE / 4) {
      int4 s = src4[idx];
      int4 d = dst4[idx];
      int p;
      p = atomicAdd(&cursor[d.x >> 8], 1); packed[p] = (s.x << 8) | (d.x & 255);
      p = atomicAdd(&cursor[d.y >> 8], 1); packed[p] = (s.y << 8) | (d.y & 255);
      p = atomicAdd(&cursor[d.z >> 8], 1); packed[p] = (s.z << 8) | (d.z & 255);
      p = atomicAdd(&cursor[d.w >> 8], 1); packed[p] = (s.w << 8) | (d.w & 255);
    }
  }
}

// csr_finalize with LOCAL scan of total[]
__global__ __launch_bounds__(256) void csr_finalize_kernel(const int* __restrict__ packed,
                                                           const int* __restrict__ total,
                                                           int* __restrict__ row_start,
                                                           int* __restrict__ csr) {
  __shared__ int fh[256];
  __shared__ int fb[256];
  int bin = blockIdx.x, tid = threadIdx.x;
  int tv = (tid < NBIN) ? total[tid] : 0;
  fb[tid] = tv;
  __syncthreads();
  for (int off = 1; off < 256; off <<= 1) {
    int t = (tid >= off) ? fb[tid - off] : 0;
    __syncthreads();
    fb[tid] += t;
    __syncthreads();
  }
  int e0 = (bin == 0) ? 0 : fb[bin - 1];
  int e1 = fb[bin];
  __syncthreads();
  fh[tid] = 0;
  __syncthreads();
  for (int e = e0 + tid; e < e1; e += 256) atomicAdd(&fh[packed[e] & 255], 1);
  __syncthreads();
  int v = fh[tid];
  fb[tid] = v;
  __syncthreads();
  for (int off = 1; off < 256; off <<= 1) {
    int t = (tid >= off) ? fb[tid - off] : 0;
    __syncthreads();
    fb[tid] += t;
    __syncthreads();
  }
  int excl = fb[tid] - v;
  int node = bin * 256 + tid;
  if (node < NN) row_start[node] = e0 + excl;
  if (bin == NBIN - 1 && tid == 0) row_start[NN] = EE;
  __syncthreads();
  fb[tid] = excl;  // cursor
  __syncthreads();
  for (int e = e0 + tid; e < e1; e += 256) {
    int p = packed[e];
    int pos = atomicAdd(&fb[p & 255], 1);
    csr[e0 + pos] = p >> 8;
  }
}

// ---------------- fused GIN aggregation + MFMA GEMM ----------------
template <bool AFF>
__global__ __launch_bounds__(256) void agg_gemm_kernel(
    const _Float16* __restrict__ x16, const int* __restrict__ row_start,
    const int* __restrict__ csr,
    const float* __restrict__ stats, const float* __restrict__ gamma,
    const float* __restrict__ beta,
    const _Float16* __restrict__ Wh, const float* __restrict__ bias,
    _Float16* __restrict__ h16out,
    float* __restrict__ ssum, float* __restrict__ ssq) {
  __shared__ _Float16 As[4][16][136];
  __shared__ float sc_s[128], sh_s[128];
  int tid = threadIdx.x;
  if (AFF) {
    if (tid < 128) {
      const float invN = 1.0f / (float)NN;
      float mm = stats[tid] * invN;
      float vv = stats[128 + tid] * invN - mm * mm;
      float rs = rsqrtf(vv + 1e-5f);
      float sc = gamma[tid] * rs;
      sc_s[tid] = sc;
      sh_s[tid] = beta[tid] - mm * sc;
    }
    __syncthreads();
  }
  int tile0 = blockIdx.x * 4;
  // ---- phase A: gather ----
  {
    int nloc = tid >> 4;  // 0..15
    int t = tid & 15;     // channel chunk
    const half8* xh8 = (const half8*)x16;
    float scv[8], shv[8];
    if (AFF) {
#pragma unroll
      for (int f = 0; f < 8; ++f) { scv[f] = sc_s[t * 8 + f]; shv[f] = sh_s[t * 8 + f]; }
    }
    for (int tt = 0; tt < 4; ++tt) {
      int tile = tile0 + tt;
      if (tile >= 3125) break;
      int node = tile * 16 + nloc;
      int s0 = row_start[node], s1 = row_start[node + 1];
      float acc[8] = {0.f, 0.f, 0.f, 0.f, 0.f, 0.f, 0.f, 0.f};
      int j = s0;
      for (; j + 8 <= s1; j += 8) {
        int i0 = csr[j + 0];
        int i1 = csr[j + 1];
        int i2 = csr[j + 2];
        int i3 = csr[j + 3];
        int i4 = csr[j + 4];
        int i5 = csr[j + 5];
        int i6 = csr[j + 6];
        int i7 = csr[j + 7];
        half8 h0 = xh8[(size_t)i0 * 16 + t];
        half8 h1 = xh8[(size_t)i1 * 16 + t];
        half8 h2 = xh8[(size_t)i2 * 16 + t];
        half8 h3 = xh8[(size_t)i3 * 16 + t];
        half8 h4 = xh8[(size_t)i4 * 16 + t];
        half8 h5 = xh8[(size_t)i5 * 16 + t];
        half8 h6 = xh8[(size_t)i6 * 16 + t];
        half8 h7 = xh8[(size_t)i7 * 16 + t];
#pragma unroll
        for (int f = 0; f < 8; ++f) {
          if (AFF) {
            acc[f] += fmaxf(fmaf((float)h0[f], scv[f], shv[f]), 0.f);
            acc[f] += fmaxf(fmaf((float)h1[f], scv[f], shv[f]), 0.f);
            acc[f] += fmaxf(fmaf((float)h2[f], scv[f], shv[f]), 0.f);
            acc[f] += fmaxf(fmaf((float)h3[f], scv[f], shv[f]), 0.f);
            acc[f] += fmaxf(fmaf((float)h4[f], scv[f], shv[f]), 0.f);
            acc[f] += fmaxf(fmaf((float)h5[f], scv[f], shv[f]), 0.f);
            acc[f] += fmaxf(fmaf((float)h6[f], scv[f], shv[f]), 0.f);
            acc[f] += fmaxf(fmaf((float)h7[f], scv[f], shv[f]), 0.f);
          } else {
            acc[f] += (((float)h0[f] + (float)h1[f]) + ((float)h2[f] + (float)h3[f])) +
                      (((float)h4[f] + (float)h5[f]) + ((float)h6[f] + (float)h7[f]));
          }
        }
      }
      if (j + 4 <= s1) {
        int i0 = csr[j + 0];
        int i1 = csr[j + 1];
        int i2 = csr[j + 2];
        int i3 = csr[j + 3];
        half8 h0 = xh8[(size_t)i0 * 16 + t];
        half8 h1 = xh8[(size_t)i1 * 16 + t];
        half8 h2 = xh8[(size_t)i2 * 16 + t];
        half8 h3 = xh8[(size_t)i3 * 16 + t];
#pragma unroll
        for (int f = 0; f < 8; ++f) {
          if (AFF) {
            acc[f] += fmaxf(fmaf((float)h0[f], scv[f], shv[f]), 0.f);
            acc[f] += fmaxf(fmaf((float)h1[f], scv[f], shv[f]), 0.f);
            acc[f] += fmaxf(fmaf((float)h2[f], scv[f], shv[f]), 0.f);
            acc[f] += fmaxf(fmaf((float)h3[f], scv[f], shv[f]), 0.f);
          } else {
            acc[f] += ((float)h0[f] + (float)h1[f]) + ((float)h2[f] + (float)h3[f]);
          }
        }
        j += 4;
      }
      for (; j < s1; ++j) {
        int i = csr[j];
        half8 h = xh8[(size_t)i * 16 + t];
#pragma unroll
        for (int f = 0; f < 8; ++f) {
          float v = (float)h[f];
          if (AFF) v = fmaxf(fmaf(v, scv[f], shv[f]), 0.f);
          acc[f] += v;
        }
      }
      half8 selfh = xh8[(size_t)node * 16 + t];
      half8 hv;
#pragma unroll
      for (int f = 0; f < 8; ++f) {
        float sv = (float)selfh[f];
        if (AFF) sv = fmaxf(fmaf(sv, scv[f], shv[f]), 0.f);
        hv[f] = (_Float16)(acc[f] + sv);
      }
      *(half8*)&As[tt][nloc][t * 8] = hv;
    }
  }
  __syncthreads();
  // ---- phase B: MFMA ----
  int w = tid >> 6, l = tid & 63;
  int lr = l & 15, lg = l >> 4;
  int cb = w * 32;
  half8 bf0[4], bf1[4];
#pragma unroll
  for (int ks = 0; ks < 4; ++ks) {
    int k = ks * 32 + lg * 8;
    bf0[ks] = *(const half8*)(Wh + (size_t)(cb + lr) * 128 + k);
    bf1[ks] = *(const half8*)(Wh + (size_t)(cb + 16 + lr) * 128 + k);
  }
  float bv0 = bias[cb + lr], bv1 = bias[cb + 16 + lr];
  float ps0 = 0.f, pq0 = 0.f, ps1 = 0.f, pq1 = 0.f;
  for (int tt = 0; tt < 4; ++tt) {
    int tile = tile0 + tt;
    if (tile >= 3125) break;
    half8 af[4];
#pragma unroll
    for (int ks = 0; ks < 4; ++ks) {
      af[ks] = *(const half8*)&As[tt][lr][ks * 32 + lg * 8];
    }
    f32x4 acc0 = {0.f, 0.f, 0.f, 0.f};
    f32x4 acc1 = {0.f, 0.f, 0.f, 0.f};
#pragma unroll
    for (int ks = 0; ks < 4; ++ks) {
      acc0 = __builtin_amdgcn_mfma_f32_16x16x32_f16(af[ks], bf0[ks], acc0, 0, 0, 0);
      acc1 = __builtin_amdgcn_mfma_f32_16x16x32_f16(af[ks], bf1[ks], acc1, 0, 0, 0);
    }
#pragma unroll
    for (int i = 0; i < 4; ++i) {
      int rr = tile * 16 + lg * 4 + i;
      float v0 = acc0[i] + bv0;
      float v1 = acc1[i] + bv1;
      h16out[(size_t)rr * 128 + cb + lr] = (_Float16)v0;
      h16out[(size_t)rr * 128 + cb + 16 + lr] = (_Float16)v1;
      ps0 += v0; pq0 += v0 * v0;
      ps1 += v1; pq1 += v1 * v1;
    }
  }
  ps0 += __shfl_xor(ps0, 16); ps0 += __shfl_xor(ps0, 32);
  pq0 += __shfl_xor(pq0, 16); pq0 += __shfl_xor(pq0, 32);
  ps1 += __shfl_xor(ps1, 16); ps1 += __shfl_xor(ps1, 32);
  pq1 += __shfl_xor(pq1, 16); pq1 += __shfl_xor(pq1, 32);
  if (lg == 0) {
    atomicAdd(&ssum[cb + lr], ps0);
    atomicAdd(&ssq[cb + lr], pq0);
    atomicAdd(&ssum[cb + 16 + lr], ps1);
    atomicAdd(&ssq[cb + 16 + lr], pq1);
  }
}

// ---------------- MFMA GIN GEMM (BN+relu on fp16 A) ----------------
template <bool BN>
__global__ __launch_bounds__(256) void gemm_gin_mfma_kernel(
    const _Float16* __restrict__ A16,
    const _Float16* __restrict__ Wh,
    const float* __restrict__ bias,
    const float* __restrict__ stats, const float* __restrict__ gamma,
    const float* __restrict__ beta,
    _Float16* __restrict__ h16out,
    float* __restrict__ ssum, float* __restrict__ ssq) {
  __shared__ float bsc_s[128], bsh_s[128];
  int tid = threadIdx.x;
  if (BN) {
    if (tid < 128) {
      const float invN = 1.0f / (float)NN;
      float mm = stats[tid] * invN;
      float vv = stats[128 + tid] * invN - mm * mm;
      float rs = rsqrtf(vv + 1e-5f);
      float sc = gamma[tid] * rs;
      bsc_s[tid] = sc;
      bsh_s[tid] = beta[tid] - mm * sc;
    }
    __syncthreads();
  }
  int w = tid >> 6, l = tid & 63;
  int lr = l & 15, lg = l >> 4;
  int cb = w * 32;
  half8 bf0[4], bf1[4];
#pragma unroll
  for (int ks = 0; ks < 4; ++ks) {
    int k = ks * 32 + lg * 8;
    bf0[ks] = *(const half8*)(Wh + (size_t)(cb + lr) * 128 + k);
    bf1[ks] = *(const half8*)(Wh + (size_t)(cb + 16 + lr) * 128 + k);
  }
  float bv0 = bias[cb + lr], bv1 = bias[cb + 16 + lr];
  float ps0 = 0.f, pq0 = 0.f, ps1 = 0.f, pq1 = 0.f;
  int t0 = blockIdx.x * 4;
  for (int t = 0; t < 4; ++t) {
    int tile = t0 + t;
    if (tile >= 3125) break;
    int r = tile * 16 + lr;
    half8 af[4];
#pragma unroll
    for (int ks = 0; ks < 4; ++ks) {
      int k0 = ks * 32 + lg * 8;
      half8 ah = *(const half8*)(A16 + (size_t)r * 128 + k0);
      if constexpr (BN) {
        float4 s0 = *(const float4*)&bsc_s[k0];
        float4 s1 = *(const float4*)&bsc_s[k0 + 4];
        float4 h0 = *(const float4*)&bsh_s[k0];
        float4 h1 = *(const float4*)&bsh_s[k0 + 4];
        half8 o;
        o[0] = (_Float16)fmaxf(fmaf((float)ah[0], s0.x, h0.x), 0.f);
        o[1] = (_Float16)fmaxf(fmaf((float)ah[1], s0.y, h0.y), 0.f);
        o[2] = (_Float16)fmaxf(fmaf((float)ah[2], s0.z, h0.z), 0.f);
        o[3] = (_Float16)fmaxf(fmaf((float)ah[3], s0.w, h0.w), 0.f);
        o[4] = (_Float16)fmaxf(fmaf((float)ah[4], s1.x, h1.x), 0.f);
        o[5] = (_Float16)fmaxf(fmaf((float)ah[5], s1.y, h1.y), 0.f);
        o[6] = (_Float16)fmaxf(fmaf((float)ah[6], s1.z, h1.z), 0.f);
        o[7] = (_Float16)fmaxf(fmaf((float)ah[7], s1.w, h1.w), 0.f);
        af[ks] = o;
      } else {
        af[ks] = ah;
      }
    }
    f32x4 acc0 = {0.f, 0.f, 0.f, 0.f};
    f32x4 acc1 = {0.f, 0.f, 0.f, 0.f};
#pragma unroll
    for (int ks = 0; ks < 4; ++ks) {
      acc0 = __builtin_amdgcn_mfma_f32_16x16x32_f16(af[ks], bf0[ks], acc0, 0, 0, 0);
      acc1 = __builtin_amdgcn_mfma_f32_16x16x32_f16(af[ks], bf1[ks], acc1, 0, 0, 0);
    }
#pragma unroll
    for (int i = 0; i < 4; ++i) {
      int rr = tile * 16 + lg * 4 + i;
      float v0 = acc0[i] + bv0;
      float v1 = acc1[i] + bv1;
      h16out[(size_t)rr * 128 + cb + lr] = (_Float16)v0;
      h16out[(size_t)rr * 128 + cb + 16 + lr] = (_Float16)v1;
      ps0 += v0; pq0 += v0 * v0;
      ps1 += v1; pq1 += v1 * v1;
    }
  }
  ps0 += __shfl_xor(ps0, 16); ps0 += __shfl_xor(ps0, 32);
  pq0 += __shfl_xor(pq0, 16); pq0 += __shfl_xor(pq0, 32);
  ps1 += __shfl_xor(ps1, 16); ps1 += __shfl_xor(ps1, 32);
  pq1 += __shfl_xor(pq1, 16); pq1 += __shfl_xor(pq1, 32);
  if (lg == 0) {
    atomicAdd(&ssum[cb + lr], ps0);
    atomicAdd(&ssq[cb + lr], pq0);
    atomicAdd(&ssum[cb + 16 + lr], ps1);
    atomicAdd(&ssq[cb + 16 + lr], pq1);
  }
}

// ---------------- fused Set2Set v10: 2 graphs per block (128 blocks) ----------
// Each wave serves BOTH graphs per weight load (shared L2 weight stream, halved
// aggregate demand). Waves 0-7 own graph A's attention rows, 8-15 graph B's.
// fp16 shadow state, atomic max/sum, fp16 LDS x-cache (144 rows/graph +
// global fallback), step-0 skip. Streaming weights (v8 style; v9's
// register-weights spilled under the 1024-thread 128-VGPR cap).
__global__ void __launch_bounds__(1024) set2set_kernel(
    const _Float16* __restrict__ x, const int* __restrict__ gptr,
    const float* __restrict__ stats, const float* __restrict__ gamma,
    const float* __restrict__ beta,
    const _Float16* __restrict__ WT0h, const _Float16* __restrict__ WTRh,
    const float* __restrict__ bc0, const float* __restrict__ bcR,
    float* __restrict__ ebuf,
    const float* __restrict__ linW, const float* __restrict__ linb,
    float* __restrict__ out) {
  __shared__ half2v xs[2][SEG2][64];    // 73728 B
  __shared__ float wpart[2][16][512];   // 65536 B (aliased as rpart in attention)
  __shared__ float hcs[2][4][128];      // 4096
  __shared__ float ccs[2][4][128];      // 4096
  __shared__ _Float16 h16s[2][4][128];  // 2048
  __shared__ _Float16 q16s[2][256];     // 1024
  __shared__ float qst[2][256];         // 2048
  __shared__ float es[2][ESC2];         // 2048
  __shared__ float bsc[128], bsh[128];  // 1024
  __shared__ unsigned smax_u[2];
  __shared__ float ssum_s[2];
  __shared__ float fred[2][2][4];

  int gA = blockIdx.x * 2;
  int tid = threadIdx.x;
  int w16 = tid >> 6, lane = tid & 63;
  int s_ = w16, cg = lane;   // matvec: K-slice (16), col-group (8 cols)
  int grs = w16 >> 3, wl = w16 & 7;  // attention/staging: graph, wave-in-graph

  // init
  if (tid < 128) {
    const float invN = 1.0f / (float)NN;
    float mm = stats[tid] * invN;
    float vv = stats[128 + tid] * invN - mm * mm;
    float rs = rsqrtf(vv + 1e-5f);
    float sc = gamma[tid] * rs;
    bsc[tid] = sc;
    bsh[tid] = beta[tid] - mm * sc;
  }
  if (tid < 256) {
    int gr = tid >> 7, j = tid & 127;
#pragma unroll
    for (int l = 0; l < 4; ++l) {
      hcs[gr][l][j] = 0.f; ccs[gr][l][j] = 0.f; h16s[gr][l][j] = (_Float16)0.f;
    }
  }
  if (tid < 512) {
    int gr = tid >> 8, idx = tid & 255;
    qst[gr][idx] = 0.f; q16s[gr][idx] = (_Float16)0.f;
  }
  __syncthreads();

  int sg0 = gptr[gA + grs], sgend = gptr[gA + grs + 1];
  int segg = sgend - sg0;
  int ncg = segg < SEG2 ? segg : SEG2;
  const half2v* xh = (const half2v*)x;
  float sc0 = bsc[2 * lane], sc1 = bsc[2 * lane + 1];
  float sh0 = bsh[2 * lane], sh1 = bsh[2 * lane + 1];
  // stage segments into LDS (BN4-transformed, fp16); 8 waves per graph
  for (int n = wl; n < ncg; n += 8) {
    half2v v = xh[(size_t)(sg0 + n) * 64 + lane];
    half2v h;
    h[0] = (_Float16)fmaxf(fmaf((float)v[0], sc0, sh0), 0.f);
    h[1] = (_Float16)fmaxf(fmaf((float)v[1], sc1, sh1), 0.f);
    xs[grs][n][lane] = h;
  }
  __syncthreads();

  for (int step = 0; step < 4; ++step) {
    // ---- 4 stacked LSTM cells (both graphs share each weight load) ----
    for (int cell = 0; cell < 4; ++cell) {
      const _Float16* WTh; const float* bias; int KP2;
      if (cell == 0) { WTh = WT0h; bias = bc0; KP2 = 12; }
      else { WTh = WTRh + (size_t)(cell - 1) * 131072; bias = bcR + (cell - 1) * 512; KP2 = 8; }
      bool skipmv = (step == 0 && cell == 0);
      if (!skipmv) {
        int se = (s_ + gA) & 15;  // rotate slice start per block
        int k20 = se * KP2;
        float a0 = 0.f, a1 = 0.f, a2 = 0.f, a3 = 0.f;
        float a4 = 0.f, a5 = 0.f, a6 = 0.f, a7 = 0.f;
        float b0 = 0.f, b1 = 0.f, b2 = 0.f, b3 = 0.f;
        float b4 = 0.f, b5 = 0.f, b6 = 0.f, b7 = 0.f;
        // step 0, cells>=1: old-h half (k>=128) is zero -> only slices se<8 contribute
        if (step != 0 || se < 8) {
          const char* wb = (const char*)WTh + (size_t)k20 * 2048 + (cg << 5);
#pragma unroll 4
          for (int k2 = 0; k2 < KP2; ++k2) {
            uint4 wa = *(const uint4*)(wb + (size_t)k2 * 2048);
            uint4 wc = *(const uint4*)(wb + (size_t)k2 * 2048 + 16);
            int kk = (k20 + k2) << 1;  // wave-uniform
            half2v iA, iB;
            if (cell == 0) {
              iA = (kk < 256) ? *(const half2v*)&q16s[0][kk]
                              : *(const half2v*)&h16s[0][0][kk - 256];
              iB = (kk < 256) ? *(const half2v*)&q16s[1][kk]
                              : *(const half2v*)&h16s[1][0][kk - 256];
            } else {
              iA = (kk < 128) ? *(const half2v*)&h16s[0][cell - 1][kk]
                              : *(const half2v*)&h16s[0][cell][kk - 128];
              iB = (kk < 128) ? *(const half2v*)&h16s[1][cell - 1][kk]
                              : *(const half2v*)&h16s[1][cell][kk - 128];
            }
            half2v v0 = __builtin_bit_cast(half2v, wa.x);
            half2v v1 = __builtin_bit_cast(half2v, wa.y);
            half2v v2 = __builtin_bit_cast(half2v, wa.z);
            half2v v3 = __builtin_bit_cast(half2v, wa.w);
            half2v v4 = __builtin_bit_cast(half2v, wc.x);
            half2v v5 = __builtin_bit_cast(half2v, wc.y);
            half2v v6 = __builtin_bit_cast(half2v, wc.z);
            half2v v7 = __builtin_bit_cast(half2v, wc.w);
            a0 = fdot2f(iA, v0, a0); b0 = fdot2f(iB, v0, b0);
            a1 = fdot2f(iA, v1, a1); b1 = fdot2f(iB, v1, b1);
            a2 = fdot2f(iA, v2, a2); b2 = fdot2f(iB, v2, b2);
            a3 = fdot2f(iA, v3, a3); b3 = fdot2f(iB, v3, b3);
            a4 = fdot2f(iA, v4, a4); b4 = fdot2f(iB, v4, b4);
            a5 = fdot2f(iA, v5, a5); b5 = fdot2f(iB, v5, b5);
            a6 = fdot2f(iA, v6, a6); b6 = fdot2f(iB, v6, b6);
            a7 = fdot2f(iA, v7, a7); b7 = fdot2f(iB, v7, b7);
          }
        }
        *(float4*)&wpart[0][s_][cg << 3] = make_float4(a0, a1, a2, a3);
        *(float4*)(&wpart[0][s_][cg << 3] + 4) = make_float4(a4, a5, a6, a7);
        *(float4*)&wpart[1][s_][cg << 3] = make_float4(b0, b1, b2, b3);
        *(float4*)(&wpart[1][s_][cg << 3] + 4) = make_float4(b4, b5, b6, b7);
        __syncthreads();
      }
      // merged gates-reduce + activation (256 threads = 2 graphs x 128)
      if (tid < 256) {
        int gr = tid >> 7, j = tid & 127;
        float4 ga = *(const float4*)&bias[4 * j];
        if (!skipmv) {
#pragma unroll
          for (int s = 0; s < 16; ++s) {
            float4 wv = *(const float4*)&wpart[gr][s][4 * j];
            ga.x += wv.x; ga.y += wv.y; ga.z += wv.z; ga.w += wv.w;
          }
        }
        float cp = ccs[gr][cell][j];
        float si = fsigm(ga.x);
        float sf = fsigm(ga.y);
        float so = fsigm(ga.w);
        float cn = sf * cp + si * ftanh(ga.z);
        ccs[gr][cell][j] = cn;
        float hn = so * ftanh(cn);
        hcs[gr][cell][j] = hn;
        h16s[gr][cell][j] = (_Float16)hn;
        if (cell == 3 && j == 0) { smax_u[gr] = 0u; ssum_s[gr] = 0.f; }
      }
      __syncthreads();
    }
    // ---- attention (per graph: 8 waves); x from fp16 LDS cache ----
    float qx = hcs[grs][3][2 * lane], qy = hcs[grs][3][2 * lane + 1];
    half2v q2; q2[0] = (_Float16)qx; q2[1] = (_Float16)qy;
    // pass 1: e + max (monotonic-key atomicMax per graph)
    float wmax = -3.0e38f;
    for (int n = wl; n < segg; n += 8) {
      float e;
      if (n < ncg) {
        e = fdot2f(xs[grs][n][lane], q2, 0.f);
      } else {
        half2v v = xh[(size_t)(sg0 + n) * 64 + lane];
        float vx = fmaxf(fmaf((float)v[0], sc0, sh0), 0.f);
        float vy = fmaxf(fmaf((float)v[1], sc1, sh1), 0.f);
        e = vx * qx + vy * qy;
      }
#pragma unroll
      for (int sh = 32; sh; sh >>= 1) e += __shfl_xor(e, sh);
      if (lane == 0) { if (n < ESC2) es[grs][n] = e; else ebuf[sg0 + n] = e; }
      wmax = fmaxf(wmax, e);
    }
    if (lane == 0) atomicMax(&smax_u[grs], keyf(wmax));
    __syncthreads();
    // pass 2: sum exp (atomicAdd per graph); cache exp for pass 3
    {
      int gr2 = tid >> 9;
      int p0g = gptr[gA + gr2];
      int segp = gptr[gA + gr2 + 1] - p0g;
      float m2 = unkeyf(smax_u[gr2]);
      float loc = 0.f;
      for (int n = tid & 511; n < segp; n += 512) {
        float e = (n < ESC2) ? es[gr2][n] : ebuf[p0g + n];
        float ex = __expf(e - m2);
        if (n < ESC2) es[gr2][n] = ex; else ebuf[p0g + n] = ex;
        loc += ex;
      }
#pragma unroll
      for (int sh = 32; sh; sh >>= 1) loc += __shfl_xor(loc, sh);
      if (lane == 0) atomicAdd(&ssum_s[gr2], loc);
    }
    __syncthreads();
    float inv = 1.0f / ssum_s[grs];
    // pass 3: r = sum a*x
    float* rp = &wpart[grs][0][0];  // alias: time-disjoint with matvec
    float rx = 0.f, ry = 0.f;
    for (int n = wl; n < segg; n += 8) {
      float ex = (n < ESC2) ? es[grs][n] : ebuf[sg0 + n];
      float coef = ex * inv;
      float vx, vy;
      if (n < ncg) {
        half2v v2 = xs[grs][n][lane];
        vx = (float)v2[0]; vy = (float)v2[1];
      } else {
        half2v v = xh[(size_t)(sg0 + n) * 64 + lane];
        vx = fmaxf(fmaf((float)v[0], sc0, sh0), 0.f);
        vy = fmaxf(fmaf((float)v[1], sc1, sh1), 0.f);
      }
      rx += coef * vx; ry += coef * vy;
    }
    rp[wl * 128 + 2 * lane] = rx;
    rp[wl * 128 + 2 * lane + 1] = ry;
    __syncthreads();
    if (tid < 256) {
      int gr = tid >> 7, j = tid & 127;
      const float* rpg = &wpart[gr][0][0];
      float r = 0.f;
#pragma unroll
      for (int t = 0; t < 8; ++t) r += rpg[t * 128 + j];
      float h3 = hcs[gr][3][j];
      qst[gr][j] = h3;
      qst[gr][128 + j] = r;
      q16s[gr][j] = (_Float16)h3;
      q16s[gr][128 + j] = (_Float16)r;
    }
    __syncthreads();
  }
  // ---- final linear (both graphs) ----
  if (tid < 512) {
    int gr = tid >> 8, idx = tid & 255;
    float val = qst[gr][idx];
    float p0 = val * linW[idx];
    float p1 = val * linW[256 + idx];
#pragma unroll
    for (int sh = 32; sh; sh >>= 1) { p0 += __shfl_xor(p0, sh); p1 += __shfl_xor(p1, sh); }
    if (lane == 0) {
      int ws = (tid >> 6) & 3;
      fred[gr][0][ws] = p0; fred[gr][1][ws] = p1;
    }
  }
  __syncthreads();
  if (tid == 0) {
    out[2 * gA + 0] = fred[0][0][0] + fred[0][0][1] + fred[0][0][2] + fred[0][0][3] + linb[0];
    out[2 * gA + 1] = fred[0][1][0] + fred[0][1][1] + fred[0][1][2] + fred[0][1][3] + linb[1];
  }
  if (tid == 64) {
    out[2 * gA + 2] = fred[1][0][0] + fred[1][0][1] + fred[1][0][2] + fred[1][0][3] + linb[0];
    out[2 * gA + 3] = fred[1][1][0] + fred[1][1][1] + fred[1][1][2] + fred[1][1][3] + linb[1];
  }
}

// ---------------- launch ----------------

extern "C" void kernel_launch(void* const* d_in, const int* in_sizes, int n_in,
                              void* d_out, int out_size, void* d_ws, size_t ws_size,
                              hipStream_t stream) {
  const float* x = (const float*)d_in[0];
  const int* ei = (const int*)d_in[1];
  const int* batch = (const int*)d_in[2];
  const float* gW[4]  = {(const float*)d_in[3],  (const float*)d_in[7],
                         (const float*)d_in[11], (const float*)d_in[15]};
  const float* gb[4]  = {(const float*)d_in[4],  (const float*)d_in[8],
                         (const float*)d_in[12], (const float*)d_in[16]};
  const float* gga[4] = {(const float*)d_in[5],  (const float*)d_in[9],
                         (const float*)d_in[13], (const float*)d_in[17]};
  const float* gbe[4] = {(const float*)d_in[6],  (const float*)d_in[10],
                         (const float*)d_in[14], (const float*)d_in[18]};
  const float* Wih0 = (const float*)d_in[19];
  const float* Whh0 = (const float*)d_in[20];
  const float* b0   = (const float*)d_in[21];
  const float* WihR = (const float*)d_in[22];
  const float* WhhR = (const float*)d_in[23];
  const float* bR   = (const float*)d_in[24];
  const float* linW = (const float*)d_in[25];
  const float* linb = (const float*)d_in[26];
  float* out = (float*)d_out;

  char* base = (char*)d_ws;
  size_t off = 0;
  auto allocf = [&](size_t n) { float* p = (float*)(base + off); off += n * sizeof(float); return p; };
  _Float16* bufA = (_Float16*)(base + off); off += 6400000 * 2;  // prep x16 / gemm4 out
  _Float16* bufB = (_Float16*)(base + off); off += 6400000 * 2;  // aggemm1 out / aggemm2 out
  _Float16* bufC = (_Float16*)(base + off); off += 6400000 * 2;  // gemm2 out
  _Float16* ginWh = (_Float16*)(base + off); off += 65536 * 2;
  _Float16* WT0h = (_Float16*)(base + off); off += 196608 * 2;
  _Float16* WTRh = (_Float16*)(base + off); off += 393216 * 2;
  float* bc0   = allocf(512);
  float* bcR   = allocf(1536);
  float* ebuf  = allocf(50000);
  // ---- zero region: stats only (1024 floats = 256 float4) ----
  float* stats = allocf(1024);     // 4 x (sum128|sq128)
  // ---- ints (all fully written before read; no zeroing needed) ----
  int* row_start = (int*)(base + off); off += 50004 * 4;
  int* gptr = (int*)(base + off); off += 260 * 4;
  int* csr = (int*)(base + off); off += 800000 * 4;
  int* packed = (int*)(base + off); off += 800000 * 4;
  int* partial = (int*)(base + off); off += NBIN * NBLK * 4;
  int* block_base = (int*)(base + off); off += NBIN * NBLK * 4;
  int* total = (int*)(base + off); off += 256 * 4;
  (void)ws_size; (void)in_sizes; (void)n_in; (void)out_size;

  // merged prep: zero | gptr | hist | weight repack | x->fp16
  prep_all_kernel<<<9211, 256, 0, stream>>>(batch, ei, gW[0], gW[1], gW[2], gW[3],
                                            Wih0, Whh0, WihR, WhhR, b0, bR, x,
                                            stats, gptr, partial, ginWh, WT0h, WTRh,
                                            bc0, bcR, bufA);
  scan_partials_kernel<<<NBIN, 256, 0, stream>>>(partial, block_base, total);
  bucket_scatter_kernel<<<NBLK, 256, 0, stream>>>(ei, total, block_base, packed);
  csr_finalize_kernel<<<NBIN, 256, 0, stream>>>(packed, total, row_start, csr);

  // GIN layer 1: fused gather+gemm1 (reads bufA, writes bufB), stats0
  agg_gemm_kernel<false><<<782, 256, 0, stream>>>(
      bufA, row_start, csr,
      nullptr, nullptr, nullptr,
      ginWh + 0 * 16384, gb[0],
      bufB, stats + 0, stats + 128);
  // gemm2: BN1+relu on bufB, writes bufC, stats1
  gemm_gin_mfma_kernel<true><<<782, 256, 0, stream>>>(
      bufB, ginWh + 1 * 16384, gb[1],
      stats + 0, gga[0], gbe[0],
      bufC, stats + 256, stats + 384);
  // GIN layer 2: fused gather(BN2+relu on bufC)+gemm3 (writes bufB), stats2
  agg_gemm_kernel<true><<<782, 256, 0, stream>>>(
      bufC, row_start, csr,
      stats + 256, gga[1], gbe[1],
      ginWh + 2 * 16384, gb[2],
      bufB, stats + 512, stats + 640);
  // gemm4: BN3+relu on bufB, writes bufA (set2set input), stats3
  gemm_gin_mfma_kernel<true><<<782, 256, 0, stream>>>(
      bufB, ginWh + 3 * 16384, gb[3],
      stats + 512, gga[2], gbe[2],
      bufA, stats + 768, stats + 896);
  // bufA holds pre-BN4 features (fp16); BN4 fused into set2set x staging

  // fused Set2Set v10: 2 graphs/block, shared weight stream
  set2set_kernel<<<128, 1024, 0, stream>>>(bufA, gptr, stats + 768, gga[3], gbe[3],
                                           WT0h, WTRh, bc0, bcR, ebuf, linW, linb, out);
}

// Round 11
// 405.239 us; speedup vs baseline: 1.4905x; 1.0877x over previous
//
#include <hip/hip_runtime.h>
#include <math.h>

#define NN 50000
#define EE 800000
#define BBG 256
#define HHC 128
#define SEG_CAP 448  // LDS x-cache rows per graph (fp16 packed)
#define ESC 512      // per-graph e-cache entries in LDS
#define NBIN 196     // coarse bins of 256 nodes
#define NBLK 196     // blocks in K1/K3 (4096 edges each)

typedef _Float16 half8 __attribute__((ext_vector_type(8)));
typedef _Float16 half4 __attribute__((ext_vector_type(4)));
typedef _Float16 half2v __attribute__((ext_vector_type(2)));
typedef float f32x4 __attribute__((ext_vector_type(4)));

#if defined(__has_builtin)
#if __has_builtin(__builtin_amdgcn_fdot2)
#define USE_FDOT2 1
#endif
#endif

__device__ __forceinline__ float fdot2f(half2v a, half2v b, float c) {
#ifdef USE_FDOT2
  return __builtin_amdgcn_fdot2(a, b, c, false);
#else
  return fmaf((float)a[0], (float)b[0], fmaf((float)a[1], (float)b[1], c));
#endif
}

__device__ __forceinline__ float fsigm(float x) {
  return __builtin_amdgcn_rcpf(1.f + __expf(-x));
}
__device__ __forceinline__ float ftanh(float x) {
  return 1.f - 2.f * __builtin_amdgcn_rcpf(1.f + __expf(2.f * x));
}

// monotonic float<->uint key for atomicMax-based float max
__device__ __forceinline__ unsigned keyf(float f) {
  unsigned u = __float_as_uint(f);
  return (u & 0x80000000u) ? ~u : (u | 0x80000000u);
}
__device__ __forceinline__ float unkeyf(unsigned k) {
  return (k & 0x80000000u) ? __uint_as_float(k ^ 0x80000000u) : __uint_as_float(~k);
}

__device__ __forceinline__ float4 aff4(float4 v, float4 sc, float4 sh) {
  v.x = fmaxf(fmaf(v.x, sc.x, sh.x), 0.f);
  v.y = fmaxf(fmaf(v.y, sc.y, sh.y), 0.f);
  v.z = fmaxf(fmaf(v.z, sc.z, sh.z), 0.f);
  v.w = fmaxf(fmaf(v.w, sc.w, sh.w), 0.f);
  return v;
}

// ---------------- merged prep: zero | gptr | coarse hist | weight repack | x->fp16 ----
__global__ __launch_bounds__(256) void prep_all_kernel(
    const int* __restrict__ batch,
    const int* __restrict__ ei,
    const float* __restrict__ W0, const float* __restrict__ W1,
    const float* __restrict__ W2, const float* __restrict__ W3,
    const float* __restrict__ Wih0, const float* __restrict__ Whh0,
    const float* __restrict__ WihR, const float* __restrict__ WhhR,
    const float* __restrict__ b0, const float* __restrict__ bR,
    const float* __restrict__ xsrc,
    float* __restrict__ stats, int* __restrict__ gptr, int* __restrict__ partial,
    _Float16* __restrict__ ginWh, _Float16* __restrict__ WT0h,
    _Float16* __restrict__ WTRh, float* __restrict__ bc0, float* __restrict__ bcR,
    _Float16* __restrict__ x16a) {
  __shared__ int hist[NBIN];
  int blk = blockIdx.x, tid = threadIdx.x;
  if (blk == 0) {
    ((float4*)stats)[tid] = make_float4(0.f, 0.f, 0.f, 0.f);  // 1024 floats
    return;
  }
  if (blk <= 196) {  // gptr boundaries
    int i = (blk - 1) * 256 + tid;
    if (i >= NN) return;
    int b = batch[i];
    int prev = (i == 0) ? -1 : batch[i - 1];
    for (int g = prev + 1; g <= b; ++g) gptr[g] = i;
    if (i == NN - 1) {
      for (int g = b + 1; g <= BBG; ++g) gptr[g] = NN;
    }
    return;
  }
  if (blk <= 392) {  // coarse hist
    int b = blk - 197;
    if (tid < NBIN) hist[tid] = 0;
    __syncthreads();
    const int4* dst4 = (const int4*)(ei + EE);
#pragma unroll
    for (int c = 0; c < 4; ++c) {
      int idx = b * 1024 + c * 256 + tid;
      if (idx < EE / 4) {
        int4 d = dst4[idx];
        atomicAdd(&hist[d.x >> 8], 1);
        atomicAdd(&hist[d.y >> 8], 1);
        atomicAdd(&hist[d.z >> 8], 1);
        atomicAdd(&hist[d.w >> 8], 1);
      }
    }
    __syncthreads();
    if (tid < NBIN) partial[tid * NBLK + b] = hist[tid];
    return;
  }
  if (blk >= 2961) {  // x -> fp16 (6250 blocks x 256 = 1,600,000 float4 groups)
    int i = (blk - 2961) * 256 + tid;
    float4 v = ((const float4*)xsrc)[i];
    half4 h;
    h[0] = (_Float16)v.x; h[1] = (_Float16)v.y;
    h[2] = (_Float16)v.z; h[3] = (_Float16)v.w;
    ((half4*)x16a)[i] = h;
    return;
  }
  // weight prep
  int idx = (blk - 393) * 256 + tid;  // [0, 657408)
  if (idx < 65536) {
    int m = idx >> 14;
    int r = idx & 16383;
    const float* W = (m == 0) ? W0 : (m == 1) ? W1 : (m == 2) ? W2 : W3;
    ginWh[idx] = (_Float16)W[r];  // natural [o][k], k contiguous
  } else if (idx < 262144) {
    int t = idx - 65536;
    int k = t >> 9, op = t & 511;
    int j = op >> 2, g = op & 3;
    int row = g * 128 + j;
    float v = (k < 256) ? Wih0[row * 256 + k] : Whh0[row * 128 + (k - 256)];
    WT0h[((k >> 1) << 10) | (op << 1) | (k & 1)] = (_Float16)v;
  } else if (idx < 655360) {
    int t = idx - 262144;
    int l = t >> 17;
    int rem = t & 131071;
    int k = rem >> 9, op = rem & 511;
    int j = op >> 2, g = op & 3;
    int row = g * 128 + j;
    float v = (k < 128) ? WihR[((size_t)l * 512 + row) * 128 + k]
                        : WhhR[((size_t)l * 512 + row) * 128 + (k - 128)];
    WTRh[((size_t)l << 17) | ((k >> 1) << 10) | (op << 1) | (k & 1)] = (_Float16)v;
  } else {
    int t = idx - 655360;
    if (t < 512) {
      bc0[t] = b0[(t & 3) * 128 + (t >> 2)];
    } else {
      int u = t - 512;
      int l = u >> 9, op = u & 511;
      bcR[u] = bR[l * 512 + (op & 3) * 128 + (op >> 2)];
    }
  }
}

// ---- atomic-free CSR build (two-level counting sort) ----

__global__ void scan_partials_kernel(const int* __restrict__ partial,
                                     int* __restrict__ block_base, int* __restrict__ total) {
  __shared__ int buf[256];
  int bin = blockIdx.x, tid = threadIdx.x;
  int v = (tid < NBLK) ? partial[bin * NBLK + tid] : 0;
  buf[tid] = v;
  __syncthreads();
  for (int off = 1; off < 256; off <<= 1) {
    int t = (tid >= off) ? buf[tid - off] : 0;
    __syncthreads();
    buf[tid] += t;
    __syncthreads();
  }
  if (tid < NBLK) block_base[bin * NBLK + tid] = buf[tid] - v;
  if (tid == 255) total[bin] = buf[255];
}

// bucket_scatter with LOCAL scan of total[]
__global__ __launch_bounds__(256) void bucket_scatter_kernel(const int* __restrict__ ei,
                                                             const int* __restrict__ total,
                                                             const int* __restrict__ block_base,
                                                             int* __restrict__ packed) {
  __shared__ int sbuf[256];
  __shared__ int cursor[NBIN];
  int tid = threadIdx.x, b = blockIdx.x;
  int v = (tid < NBIN) ? total[tid] : 0;
  sbuf[tid] = v;
  __syncthreads();
  for (int off = 1; off < 256; off <<= 1) {
    int t = (tid >= off) ? sbuf[tid - off] : 0;
    __syncthreads();
    sbuf[tid] += t;
    __syncthreads();
  }
  if (tid < NBIN) cursor[tid] = (sbuf[tid] - v) + block_base[tid * NBLK + b];
  __syncthreads();
  const int4* src4 = (const int4*)ei;
  const int4* dst4 = (const int4*)(ei + EE);
#pragma unroll
  for (int c = 0; c < 4; ++c) {
    int idx = b * 1024 + c * 256 + tid;
    if (idx < EE / 4) {
      int4 s = src4[idx];
      int4 d = dst4[idx];
      int p;
      p = atomicAdd(&cursor[d.x >> 8], 1); packed[p] = (s.x << 8) | (d.x & 255);
      p = atomicAdd(&cursor[d.y >> 8], 1); packed[p] = (s.y << 8) | (d.y & 255);
      p = atomicAdd(&cursor[d.z >> 8], 1); packed[p] = (s.z << 8) | (d.z & 255);
      p = atomicAdd(&cursor[d.w >> 8], 1); packed[p] = (s.w << 8) | (d.w & 255);
    }
  }
}

// csr_finalize with LOCAL scan of total[]
__global__ __launch_bounds__(256) void csr_finalize_kernel(const int* __restrict__ packed,
                                                           const int* __restrict__ total,
                                                           int* __restrict__ row_start,
                                                           int* __restrict__ csr) {
  __shared__ int fh[256];
  __shared__ int fb[256];
  int bin = blockIdx.x, tid = threadIdx.x;
  int tv = (tid < NBIN) ? total[tid] : 0;
  fb[tid] = tv;
  __syncthreads();
  for (int off = 1; off < 256; off <<= 1) {
    int t = (tid >= off) ? fb[tid - off] : 0;
    __syncthreads();
    fb[tid] += t;
    __syncthreads();
  }
  int e0 = (bin == 0) ? 0 : fb[bin - 1];
  int e1 = fb[bin];
  __syncthreads();
  fh[tid] = 0;
  __syncthreads();
  for (int e = e0 + tid; e < e1; e += 256) atomicAdd(&fh[packed[e] & 255], 1);
  __syncthreads();
  int v = fh[tid];
  fb[tid] = v;
  __syncthreads();
  for (int off = 1; off < 256; off <<= 1) {
    int t = (tid >= off) ? fb[tid - off] : 0;
    __syncthreads();
    fb[tid] += t;
    __syncthreads();
  }
  int excl = fb[tid] - v;
  int node = bin * 256 + tid;
  if (node < NN) row_start[node] = e0 + excl;
  if (bin == NBIN - 1 && tid == 0) row_start[NN] = EE;
  __syncthreads();
  fb[tid] = excl;  // cursor
  __syncthreads();
  for (int e = e0 + tid; e < e1; e += 256) {
    int p = packed[e];
    int pos = atomicAdd(&fb[p & 255], 1);
    csr[e0 + pos] = p >> 8;
  }
}

// ---------------- fused GIN aggregation + MFMA GEMM ----------------
template <bool AFF>
__global__ __launch_bounds__(256) void agg_gemm_kernel(
    const _Float16* __restrict__ x16, const int* __restrict__ row_start,
    const int* __restrict__ csr,
    const float* __restrict__ stats, const float* __restrict__ gamma,
    const float* __restrict__ beta,
    const _Float16* __restrict__ Wh, const float* __restrict__ bias,
    _Float16* __restrict__ h16out,
    float* __restrict__ ssum, float* __restrict__ ssq) {
  __shared__ _Float16 As[4][16][136];
  __shared__ float sc_s[128], sh_s[128];
  int tid = threadIdx.x;
  if (AFF) {
    if (tid < 128) {
      const float invN = 1.0f / (float)NN;
      float mm = stats[tid] * invN;
      float vv = stats[128 + tid] * invN - mm * mm;
      float rs = rsqrtf(vv + 1e-5f);
      float sc = gamma[tid] * rs;
      sc_s[tid] = sc;
      sh_s[tid] = beta[tid] - mm * sc;
    }
    __syncthreads();
  }
  int tile0 = blockIdx.x * 4;
  // ---- phase A: gather ----
  {
    int nloc = tid >> 4;  // 0..15
    int t = tid & 15;     // channel chunk
    const half8* xh8 = (const half8*)x16;
    float scv[8], shv[8];
    if (AFF) {
#pragma unroll
      for (int f = 0; f < 8; ++f) { scv[f] = sc_s[t * 8 + f]; shv[f] = sh_s[t * 8 + f]; }
    }
    for (int tt = 0; tt < 4; ++tt) {
      int tile = tile0 + tt;
      if (tile >= 3125) break;
      int node = tile * 16 + nloc;
      int s0 = row_start[node], s1 = row_start[node + 1];
      float acc[8] = {0.f, 0.f, 0.f, 0.f, 0.f, 0.f, 0.f, 0.f};
      int j = s0;
      for (; j + 8 <= s1; j += 8) {
        int i0 = csr[j + 0];
        int i1 = csr[j + 1];
        int i2 = csr[j + 2];
        int i3 = csr[j + 3];
        int i4 = csr[j + 4];
        int i5 = csr[j + 5];
        int i6 = csr[j + 6];
        int i7 = csr[j + 7];
        half8 h0 = xh8[(size_t)i0 * 16 + t];
        half8 h1 = xh8[(size_t)i1 * 16 + t];
        half8 h2 = xh8[(size_t)i2 * 16 + t];
        half8 h3 = xh8[(size_t)i3 * 16 + t];
        half8 h4 = xh8[(size_t)i4 * 16 + t];
        half8 h5 = xh8[(size_t)i5 * 16 + t];
        half8 h6 = xh8[(size_t)i6 * 16 + t];
        half8 h7 = xh8[(size_t)i7 * 16 + t];
#pragma unroll
        for (int f = 0; f < 8; ++f) {
          if (AFF) {
            acc[f] += fmaxf(fmaf((float)h0[f], scv[f], shv[f]), 0.f);
            acc[f] += fmaxf(fmaf((float)h1[f], scv[f], shv[f]), 0.f);
            acc[f] += fmaxf(fmaf((float)h2[f], scv[f], shv[f]), 0.f);
            acc[f] += fmaxf(fmaf((float)h3[f], scv[f], shv[f]), 0.f);
            acc[f] += fmaxf(fmaf((float)h4[f], scv[f], shv[f]), 0.f);
            acc[f] += fmaxf(fmaf((float)h5[f], scv[f], shv[f]), 0.f);
            acc[f] += fmaxf(fmaf((float)h6[f], scv[f], shv[f]), 0.f);
            acc[f] += fmaxf(fmaf((float)h7[f], scv[f], shv[f]), 0.f);
          } else {
            acc[f] += (((float)h0[f] + (float)h1[f]) + ((float)h2[f] + (float)h3[f])) +
                      (((float)h4[f] + (float)h5[f]) + ((float)h6[f] + (float)h7[f]));
          }
        }
      }
      if (j + 4 <= s1) {
        int i0 = csr[j + 0];
        int i1 = csr[j + 1];
        int i2 = csr[j + 2];
        int i3 = csr[j + 3];
        half8 h0 = xh8[(size_t)i0 * 16 + t];
        half8 h1 = xh8[(size_t)i1 * 16 + t];
        half8 h2 = xh8[(size_t)i2 * 16 + t];
        half8 h3 = xh8[(size_t)i3 * 16 + t];
#pragma unroll
        for (int f = 0; f < 8; ++f) {
          if (AFF) {
            acc[f] += fmaxf(fmaf((float)h0[f], scv[f], shv[f]), 0.f);
            acc[f] += fmaxf(fmaf((float)h1[f], scv[f], shv[f]), 0.f);
            acc[f] += fmaxf(fmaf((float)h2[f], scv[f], shv[f]), 0.f);
            acc[f] += fmaxf(fmaf((float)h3[f], scv[f], shv[f]), 0.f);
          } else {
            acc[f] += ((float)h0[f] + (float)h1[f]) + ((float)h2[f] + (float)h3[f]);
          }
        }
        j += 4;
      }
      for (; j < s1; ++j) {
        int i = csr[j];
        half8 h = xh8[(size_t)i * 16 + t];
#pragma unroll
        for (int f = 0; f < 8; ++f) {
          float v = (float)h[f];
          if (AFF) v = fmaxf(fmaf(v, scv[f], shv[f]), 0.f);
          acc[f] += v;
        }
      }
      half8 selfh = xh8[(size_t)node * 16 + t];
      half8 hv;
#pragma unroll
      for (int f = 0; f < 8; ++f) {
        float sv = (float)selfh[f];
        if (AFF) sv = fmaxf(fmaf(sv, scv[f], shv[f]), 0.f);
        hv[f] = (_Float16)(acc[f] + sv);
      }
      *(half8*)&As[tt][nloc][t * 8] = hv;
    }
  }
  __syncthreads();
  // ---- phase B: MFMA ----
  int w = tid >> 6, l = tid & 63;
  int lr = l & 15, lg = l >> 4;
  int cb = w * 32;
  half8 bf0[4], bf1[4];
#pragma unroll
  for (int ks = 0; ks < 4; ++ks) {
    int k = ks * 32 + lg * 8;
    bf0[ks] = *(const half8*)(Wh + (size_t)(cb + lr) * 128 + k);
    bf1[ks] = *(const half8*)(Wh + (size_t)(cb + 16 + lr) * 128 + k);
  }
  float bv0 = bias[cb + lr], bv1 = bias[cb + 16 + lr];
  float ps0 = 0.f, pq0 = 0.f, ps1 = 0.f, pq1 = 0.f;
  for (int tt = 0; tt < 4; ++tt) {
    int tile = tile0 + tt;
    if (tile >= 3125) break;
    half8 af[4];
#pragma unroll
    for (int ks = 0; ks < 4; ++ks) {
      af[ks] = *(const half8*)&As[tt][lr][ks * 32 + lg * 8];
    }
    f32x4 acc0 = {0.f, 0.f, 0.f, 0.f};
    f32x4 acc1 = {0.f, 0.f, 0.f, 0.f};
#pragma unroll
    for (int ks = 0; ks < 4; ++ks) {
      acc0 = __builtin_amdgcn_mfma_f32_16x16x32_f16(af[ks], bf0[ks], acc0, 0, 0, 0);
      acc1 = __builtin_amdgcn_mfma_f32_16x16x32_f16(af[ks], bf1[ks], acc1, 0, 0, 0);
    }
#pragma unroll
    for (int i = 0; i < 4; ++i) {
      int rr = tile * 16 + lg * 4 + i;
      float v0 = acc0[i] + bv0;
      float v1 = acc1[i] + bv1;
      h16out[(size_t)rr * 128 + cb + lr] = (_Float16)v0;
      h16out[(size_t)rr * 128 + cb + 16 + lr] = (_Float16)v1;
      ps0 += v0; pq0 += v0 * v0;
      ps1 += v1; pq1 += v1 * v1;
    }
  }
  ps0 += __shfl_xor(ps0, 16); ps0 += __shfl_xor(ps0, 32);
  pq0 += __shfl_xor(pq0, 16); pq0 += __shfl_xor(pq0, 32);
  ps1 += __shfl_xor(ps1, 16); ps1 += __shfl_xor(ps1, 32);
  pq1 += __shfl_xor(pq1, 16); pq1 += __shfl_xor(pq1, 32);
  if (lg == 0) {
    atomicAdd(&ssum[cb + lr], ps0);
    atomicAdd(&ssq[cb + lr], pq0);
    atomicAdd(&ssum[cb + 16 + lr], ps1);
    atomicAdd(&ssq[cb + 16 + lr], pq1);
  }
}

// ---------------- MFMA GIN GEMM (BN+relu on fp16 A) ----------------
template <bool BN>
__global__ __launch_bounds__(256) void gemm_gin_mfma_kernel(
    const _Float16* __restrict__ A16,
    const _Float16* __restrict__ Wh,
    const float* __restrict__ bias,
    const float* __restrict__ stats, const float* __restrict__ gamma,
    const float* __restrict__ beta,
    _Float16* __restrict__ h16out,
    float* __restrict__ ssum, float* __restrict__ ssq) {
  __shared__ float bsc_s[128], bsh_s[128];
  int tid = threadIdx.x;
  if (BN) {
    if (tid < 128) {
      const float invN = 1.0f / (float)NN;
      float mm = stats[tid] * invN;
      float vv = stats[128 + tid] * invN - mm * mm;
      float rs = rsqrtf(vv + 1e-5f);
      float sc = gamma[tid] * rs;
      bsc_s[tid] = sc;
      bsh_s[tid] = beta[tid] - mm * sc;
    }
    __syncthreads();
  }
  int w = tid >> 6, l = tid & 63;
  int lr = l & 15, lg = l >> 4;
  int cb = w * 32;
  half8 bf0[4], bf1[4];
#pragma unroll
  for (int ks = 0; ks < 4; ++ks) {
    int k = ks * 32 + lg * 8;
    bf0[ks] = *(const half8*)(Wh + (size_t)(cb + lr) * 128 + k);
    bf1[ks] = *(const half8*)(Wh + (size_t)(cb + 16 + lr) * 128 + k);
  }
  float bv0 = bias[cb + lr], bv1 = bias[cb + 16 + lr];
  float ps0 = 0.f, pq0 = 0.f, ps1 = 0.f, pq1 = 0.f;
  int t0 = blockIdx.x * 4;
  for (int t = 0; t < 4; ++t) {
    int tile = t0 + t;
    if (tile >= 3125) break;
    int r = tile * 16 + lr;
    half8 af[4];
#pragma unroll
    for (int ks = 0; ks < 4; ++ks) {
      int k0 = ks * 32 + lg * 8;
      half8 ah = *(const half8*)(A16 + (size_t)r * 128 + k0);
      if constexpr (BN) {
        float4 s0 = *(const float4*)&bsc_s[k0];
        float4 s1 = *(const float4*)&bsc_s[k0 + 4];
        float4 h0 = *(const float4*)&bsh_s[k0];
        float4 h1 = *(const float4*)&bsh_s[k0 + 4];
        half8 o;
        o[0] = (_Float16)fmaxf(fmaf((float)ah[0], s0.x, h0.x), 0.f);
        o[1] = (_Float16)fmaxf(fmaf((float)ah[1], s0.y, h0.y), 0.f);
        o[2] = (_Float16)fmaxf(fmaf((float)ah[2], s0.z, h0.z), 0.f);
        o[3] = (_Float16)fmaxf(fmaf((float)ah[3], s0.w, h0.w), 0.f);
        o[4] = (_Float16)fmaxf(fmaf((float)ah[4], s1.x, h1.x), 0.f);
        o[5] = (_Float16)fmaxf(fmaf((float)ah[5], s1.y, h1.y), 0.f);
        o[6] = (_Float16)fmaxf(fmaf((float)ah[6], s1.z, h1.z), 0.f);
        o[7] = (_Float16)fmaxf(fmaf((float)ah[7], s1.w, h1.w), 0.f);
        af[ks] = o;
      } else {
        af[ks] = ah;
      }
    }
    f32x4 acc0 = {0.f, 0.f, 0.f, 0.f};
    f32x4 acc1 = {0.f, 0.f, 0.f, 0.f};
#pragma unroll
    for (int ks = 0; ks < 4; ++ks) {
      acc0 = __builtin_amdgcn_mfma_f32_16x16x32_f16(af[ks], bf0[ks], acc0, 0, 0, 0);
      acc1 = __builtin_amdgcn_mfma_f32_16x16x32_f16(af[ks], bf1[ks], acc1, 0, 0, 0);
    }
#pragma unroll
    for (int i = 0; i < 4; ++i) {
      int rr = tile * 16 + lg * 4 + i;
      float v0 = acc0[i] + bv0;
      float v1 = acc1[i] + bv1;
      h16out[(size_t)rr * 128 + cb + lr] = (_Float16)v0;
      h16out[(size_t)rr * 128 + cb + 16 + lr] = (_Float16)v1;
      ps0 += v0; pq0 += v0 * v0;
      ps1 += v1; pq1 += v1 * v1;
    }
  }
  ps0 += __shfl_xor(ps0, 16); ps0 += __shfl_xor(ps0, 32);
  pq0 += __shfl_xor(pq0, 16); pq0 += __shfl_xor(pq0, 32);
  ps1 += __shfl_xor(ps1, 16); ps1 += __shfl_xor(ps1, 32);
  pq1 += __shfl_xor(pq1, 16); pq1 += __shfl_xor(pq1, 32);
  if (lg == 0) {
    atomicAdd(&ssum[cb + lr], ps0);
    atomicAdd(&ssq[cb + lr], pq0);
    atomicAdd(&ssum[cb + 16 + lr], ps1);
    atomicAdd(&ssq[cb + 16 + lr], pq1);
  }
}

// ---------------- fused Set2Set v8 (reverted from v10): fp16 shadow state,
// atomic max/sum, fp16 LDS x-cache, step-0 skip, streaming weights ----------
__global__ void __launch_bounds__(1024) set2set_kernel(
    const _Float16* __restrict__ x, const int* __restrict__ gptr,
    const float* __restrict__ stats, const float* __restrict__ gamma,
    const float* __restrict__ beta,
    const _Float16* __restrict__ WT0h, const _Float16* __restrict__ WTRh,
    const float* __restrict__ bc0, const float* __restrict__ bcR,
    float* __restrict__ ebuf,
    const float* __restrict__ linW, const float* __restrict__ linb,
    float* __restrict__ out) {
  __shared__ half2v xs[SEG_CAP * 64];   // 114688 B (448 rows, fp16-packed)
  __shared__ float wpart[16][512];      // 32 KB (aliased as rpart in attention)
  __shared__ float hcs[4][128];
  __shared__ float ccs[4][128];
  __shared__ _Float16 h16s[4][128];     // fp16 shadow of hcs (matvec operand)
  __shared__ _Float16 q16s[256];        // fp16 shadow of qst
  __shared__ float qst[256];
  __shared__ float es[ESC];             // 2 KB
  __shared__ float bsc[128], bsh[128];
  __shared__ unsigned smax_u;
  __shared__ float ssum_s;
  __shared__ float fred[2][4];

  int g = blockIdx.x, tid = threadIdx.x;
  int w16 = tid >> 6, lane = tid & 63;

  // init
  if (tid < 128) {
    const float invN = 1.0f / (float)NN;
    float mm = stats[tid] * invN;
    float vv = stats[128 + tid] * invN - mm * mm;
    float rs = rsqrtf(vv + 1e-5f);
    float sc = gamma[tid] * rs;
    bsc[tid] = sc;
    bsh[tid] = beta[tid] - mm * sc;
#pragma unroll
    for (int l = 0; l < 4; ++l) {
      hcs[l][tid] = 0.f; ccs[l][tid] = 0.f; h16s[l][tid] = (_Float16)0.f;
    }
  }
  if (tid < 256) { qst[tid] = 0.f; q16s[tid] = (_Float16)0.f; }
  __syncthreads();

  int s0 = gptr[g], s1 = gptr[g + 1];
  int seg = s1 - s0;
  int ncache = seg < SEG_CAP ? seg : SEG_CAP;
  const half2v* xh = (const half2v*)x;
  float sc0 = bsc[2 * lane], sc1 = bsc[2 * lane + 1];
  float sh0 = bsh[2 * lane], sh1 = bsh[2 * lane + 1];
  // stage segment into LDS once (BN4-transformed, fp16-packed); one row per wave
  for (int n = w16; n < ncache; n += 16) {
    half2v v = xh[(size_t)(s0 + n) * 64 + lane];
    half2v h;
    h[0] = (_Float16)fmaxf(fmaf((float)v[0], sc0, sh0), 0.f);
    h[1] = (_Float16)fmaxf(fmaf((float)v[1], sc1, sh1), 0.f);
    xs[n * 64 + lane] = h;
  }
  __syncthreads();

  int s_ = tid >> 6, cg = tid & 63;  // matvec: K-slice (16), col-group (8 cols)

  for (int step = 0; step < 4; ++step) {
    // ---- 4 stacked LSTM cells ----
    for (int cell = 0; cell < 4; ++cell) {
      const _Float16* WTh; const float* bias; int KP2;
      if (cell == 0) {
        WTh = WT0h; bias = bc0; KP2 = 12;  // K=384 -> 192 k2-pairs, 12 per slice
      } else {
        WTh = WTRh + (size_t)(cell - 1) * 131072;
        bias = bcR + (cell - 1) * 512; KP2 = 8;  // K=256 -> 128 pairs, 8 per slice
      }
      bool skipmv = (step == 0 && cell == 0);
      if (!skipmv) {
        int se = (s_ + g) & 15;  // rotate slice start per block
        int k20 = se * KP2;
        float a0 = 0.f, a1 = 0.f, a2 = 0.f, a3 = 0.f;
        float a4 = 0.f, a5 = 0.f, a6 = 0.f, a7 = 0.f;
        // step 0, cells>=1: old-h half is zero -> only slices se<8 contribute
        if (step != 0 || se < 8) {
          const char* wb = (const char*)WTh + (size_t)k20 * 2048 + (cg << 5);
#pragma unroll 4
          for (int k2 = 0; k2 < KP2; ++k2) {
            uint4 wa = *(const uint4*)(wb + (size_t)k2 * 2048);
            uint4 wc = *(const uint4*)(wb + (size_t)k2 * 2048 + 16);
            int kk = (k20 + k2) << 1;  // wave-uniform
            half2v i2;
            if (cell == 0) {
              i2 = (kk < 256) ? *(const half2v*)&q16s[kk]
                              : *(const half2v*)&h16s[0][kk - 256];
            } else {
              i2 = (kk < 128) ? *(const half2v*)&h16s[cell - 1][kk]
                              : *(const half2v*)&h16s[cell][kk - 128];
            }
            a0 = fdot2f(i2, __builtin_bit_cast(half2v, wa.x), a0);
            a1 = fdot2f(i2, __builtin_bit_cast(half2v, wa.y), a1);
            a2 = fdot2f(i2, __builtin_bit_cast(half2v, wa.z), a2);
            a3 = fdot2f(i2, __builtin_bit_cast(half2v, wa.w), a3);
            a4 = fdot2f(i2, __builtin_bit_cast(half2v, wc.x), a4);
            a5 = fdot2f(i2, __builtin_bit_cast(half2v, wc.y), a5);
            a6 = fdot2f(i2, __builtin_bit_cast(half2v, wc.z), a6);
            a7 = fdot2f(i2, __builtin_bit_cast(half2v, wc.w), a7);
          }
        }
        *(float4*)&wpart[s_][cg << 3] = make_float4(a0, a1, a2, a3);
        *(float4*)(&wpart[s_][cg << 3] + 4) = make_float4(a4, a5, a6, a7);
        __syncthreads();
      }
      // merged gates-reduce + activation (128 threads, float4 over 16 slices)
      if (tid < 128) {
        int j = tid;
        float4 ga = *(const float4*)&bias[4 * j];
        if (!skipmv) {
#pragma unroll
          for (int s = 0; s < 16; ++s) {
            float4 wv = *(const float4*)&wpart[s][4 * j];
            ga.x += wv.x; ga.y += wv.y; ga.z += wv.z; ga.w += wv.w;
          }
        }
        float cp = ccs[cell][j];
        float si = fsigm(ga.x);
        float sf = fsigm(ga.y);
        float so = fsigm(ga.w);
        float cn = sf * cp + si * ftanh(ga.z);
        ccs[cell][j] = cn;
        float hn = so * ftanh(cn);
        hcs[cell][j] = hn;
        h16s[cell][j] = (_Float16)hn;
        if (cell == 3 && j == 0) { smax_u = 0u; ssum_s = 0.f; }
      }
      __syncthreads();
    }
    // ---- attention, q = new h[3]; x from fp16 LDS cache ----
    float* rpart = &wpart[0][0];  // alias: time-disjoint with matvec
    float qx = hcs[3][2 * lane], qy = hcs[3][2 * lane + 1];
    half2v q2; q2[0] = (_Float16)qx; q2[1] = (_Float16)qy;
    // pass 1: e + max (block max via monotonic-key atomicMax, 1 barrier)
    float wmax = -3.0e38f;
    for (int n = w16; n < seg; n += 16) {
      float e;
      if (n < ncache) {
        e = fdot2f(xs[n * 64 + lane], q2, 0.f);
      } else {
        half2v v = xh[(size_t)(s0 + n) * 64 + lane];
        float vx = fmaxf(fmaf((float)v[0], sc0, sh0), 0.f);
        float vy = fmaxf(fmaf((float)v[1], sc1, sh1), 0.f);
        e = vx * qx + vy * qy;
      }
#pragma unroll
      for (int sh = 32; sh; sh >>= 1) e += __shfl_xor(e, sh);
      if (lane == 0) { if (n < ESC) es[n] = e; else ebuf[s0 + n] = e; }
      wmax = fmaxf(wmax, e);
    }
    if (lane == 0) atomicMax(&smax_u, keyf(wmax));
    __syncthreads();
    float m = unkeyf(smax_u);
    // pass 2: sum exp (atomicAdd, 1 barrier); cache exp for pass 3
    float loc = 0.f;
    for (int n = tid; n < seg; n += 1024) {
      float e = (n < ESC) ? es[n] : ebuf[s0 + n];
      float ex = __expf(e - m);
      if (n < ESC) es[n] = ex; else ebuf[s0 + n] = ex;
      loc += ex;
    }
#pragma unroll
    for (int sh = 32; sh; sh >>= 1) loc += __shfl_xor(loc, sh);
    if (lane == 0) atomicAdd(&ssum_s, loc);
    __syncthreads();
    float inv = 1.0f / ssum_s;
    // pass 3: r = sum a*x
    float rx = 0.f, ry = 0.f;
    for (int n = w16; n < seg; n += 16) {
      float ex = (n < ESC) ? es[n] : ebuf[s0 + n];
      float coef = ex * inv;
      float vx, vy;
      if (n < ncache) {
        half2v v2 = xs[n * 64 + lane];
        vx = (float)v2[0]; vy = (float)v2[1];
      } else {
        half2v v = xh[(size_t)(s0 + n) * 64 + lane];
        vx = fmaxf(fmaf((float)v[0], sc0, sh0), 0.f);
        vy = fmaxf(fmaf((float)v[1], sc1, sh1), 0.f);
      }
      rx += coef * vx; ry += coef * vy;
    }
    rpart[w16 * 128 + 2 * lane] = rx;
    rpart[w16 * 128 + 2 * lane + 1] = ry;
    __syncthreads();
    if (tid < 128) {
      float r = 0.f;
#pragma unroll
      for (int t = 0; t < 16; ++t) r += rpart[t * 128 + tid];
      float h3 = hcs[3][tid];
      qst[tid] = h3;
      qst[128 + tid] = r;
      q16s[tid] = (_Float16)h3;
      q16s[128 + tid] = (_Float16)r;
    }
    __syncthreads();
  }
  // ---- final linear ----
  if (tid < 256) {
    float val = qst[tid];
    float p0 = val * linW[tid];
    float p1 = val * linW[256 + tid];
#pragma unroll
    for (int sh = 32; sh; sh >>= 1) { p0 += __shfl_xor(p0, sh); p1 += __shfl_xor(p1, sh); }
    if (lane == 0) { fred[0][w16] = p0; fred[1][w16] = p1; }
  }
  __syncthreads();
  if (tid == 0) {
    out[2 * g + 0] = fred[0][0] + fred[0][1] + fred[0][2] + fred[0][3] + linb[0];
    out[2 * g + 1] = fred[1][0] + fred[1][1] + fred[1][2] + fred[1][3] + linb[1];
  }
}

// ---------------- launch ----------------

extern "C" void kernel_launch(void* const* d_in, const int* in_sizes, int n_in,
                              void* d_out, int out_size, void* d_ws, size_t ws_size,
                              hipStream_t stream) {
  const float* x = (const float*)d_in[0];
  const int* ei = (const int*)d_in[1];
  const int* batch = (const int*)d_in[2];
  const float* gW[4]  = {(const float*)d_in[3],  (const float*)d_in[7],
                         (const float*)d_in[11], (const float*)d_in[15]};
  const float* gb[4]  = {(const float*)d_in[4],  (const float*)d_in[8],
                         (const float*)d_in[12], (const float*)d_in[16]};
  const float* gga[4] = {(const float*)d_in[5],  (const float*)d_in[9],
                         (const float*)d_in[13], (const float*)d_in[17]};
  const float* gbe[4] = {(const float*)d_in[6],  (const float*)d_in[10],
                         (const float*)d_in[14], (const float*)d_in[18]};
  const float* Wih0 = (const float*)d_in[19];
  const float* Whh0 = (const float*)d_in[20];
  const float* b0   = (const float*)d_in[21];
  const float* WihR = (const float*)d_in[22];
  const float* WhhR = (const float*)d_in[23];
  const float* bR   = (const float*)d_in[24];
  const float* linW = (const float*)d_in[25];
  const float* linb = (const float*)d_in[26];
  float* out = (float*)d_out;

  char* base = (char*)d_ws;
  size_t off = 0;
  auto allocf = [&](size_t n) { float* p = (float*)(base + off); off += n * sizeof(float); return p; };
  // two-buffer ping-pong: prep->A, agg1 A->B, gemm2 B->A, agg2 A->B, gemm4 B->A
  _Float16* bufA = (_Float16*)(base + off); off += 6400000 * 2;
  _Float16* bufB = (_Float16*)(base + off); off += 6400000 * 2;
  _Float16* ginWh = (_Float16*)(base + off); off += 65536 * 2;
  _Float16* WT0h = (_Float16*)(base + off); off += 196608 * 2;
  _Float16* WTRh = (_Float16*)(base + off); off += 393216 * 2;
  float* bc0   = allocf(512);
  float* bcR   = allocf(1536);
  float* ebuf  = allocf(50000);
  // ---- zero region: stats only (1024 floats = 256 float4) ----
  float* stats = allocf(1024);     // 4 x (sum128|sq128)
  // ---- ints (all fully written before read; no zeroing needed) ----
  int* row_start = (int*)(base + off); off += 50004 * 4;
  int* gptr = (int*)(base + off); off += 260 * 4;
  int* csr = (int*)(base + off); off += 800000 * 4;
  int* packed = (int*)(base + off); off += 800000 * 4;
  int* partial = (int*)(base + off); off += NBIN * NBLK * 4;
  int* block_base = (int*)(base + off); off += NBIN * NBLK * 4;
  int* total = (int*)(base + off); off += 256 * 4;
  (void)ws_size; (void)in_sizes; (void)n_in; (void)out_size;

  // merged prep: zero | gptr | hist | weight repack | x->fp16
  prep_all_kernel<<<9211, 256, 0, stream>>>(batch, ei, gW[0], gW[1], gW[2], gW[3],
                                            Wih0, Whh0, WihR, WhhR, b0, bR, x,
                                            stats, gptr, partial, ginWh, WT0h, WTRh,
                                            bc0, bcR, bufA);
  scan_partials_kernel<<<NBIN, 256, 0, stream>>>(partial, block_base, total);
  bucket_scatter_kernel<<<NBLK, 256, 0, stream>>>(ei, total, block_base, packed);
  csr_finalize_kernel<<<NBIN, 256, 0, stream>>>(packed, total, row_start, csr);

  // GIN layer 1: fused gather+gemm1 (reads bufA, writes bufB), stats0
  agg_gemm_kernel<false><<<782, 256, 0, stream>>>(
      bufA, row_start, csr,
      nullptr, nullptr, nullptr,
      ginWh + 0 * 16384, gb[0],
      bufB, stats + 0, stats + 128);
  // gemm2: BN1+relu on bufB, writes bufA (prep-x16 fully consumed by agg1), stats1
  gemm_gin_mfma_kernel<true><<<782, 256, 0, stream>>>(
      bufB, ginWh + 1 * 16384, gb[1],
      stats + 0, gga[0], gbe[0],
      bufA, stats + 256, stats + 384);
  // GIN layer 2: fused gather(BN2+relu on bufA)+gemm3 (writes bufB), stats2
  agg_gemm_kernel<true><<<782, 256, 0, stream>>>(
      bufA, row_start, csr,
      stats + 256, gga[1], gbe[1],
      ginWh + 2 * 16384, gb[2],
      bufB, stats + 512, stats + 640);
  // gemm4: BN3+relu on bufB, writes bufA (set2set input), stats3
  gemm_gin_mfma_kernel<true><<<782, 256, 0, stream>>>(
      bufB, ginWh + 3 * 16384, gb[3],
      stats + 512, gga[2], gbe[2],
      bufA, stats + 768, stats + 896);
  // bufA holds pre-BN4 features (fp16); BN4 fused into set2set x staging

  // fused Set2Set v8 (reverted, proven 84 us)
  set2set_kernel<<<256, 1024, 0, stream>>>(bufA, gptr, stats + 768, gga[3], gbe[3],
                                           WT0h, WTRh, bc0, bcR, ebuf, linW, linb, out);
}